// Round 6
// baseline (736.654 us; speedup 1.0000x reference)
//
#include <hip/hip_runtime.h>

#define HH 256
#define WW 256
#define CC 32
#define HWSZ (HH * WW)
#define IMGSZ (CC * HWSZ)
#define NIMG 8
#define EPSV 1e-8f
#define NCH (CC / 2)   // channels per lane (2-way channel split)

// Prefetch slot: 3 row float4s + the 3 edge scalars (only meaningful for
// lanes tx==0 / tx==31; zero elsewhere / at image borders).
struct Slot { float4 m0, m1, m2; float e0, e1, e2; };

template <bool YEDGE>
__device__ __forceinline__ void load_slot(Slot& s, const float* __restrict__ p,
                                          bool ym, bool yp, bool xl, bool xr, int tx)
{
    float4 z; z.x = z.y = z.z = z.w = 0.f;
    s.m1 = *reinterpret_cast<const float4*>(p);
    if (YEDGE) {
        s.m0 = ym ? *reinterpret_cast<const float4*>(p - WW) : z;
        s.m2 = yp ? *reinterpret_cast<const float4*>(p + WW) : z;
    } else {
        s.m0 = *reinterpret_cast<const float4*>(p - WW);
        s.m2 = *reinterpret_cast<const float4*>(p + WW);
    }
    s.e0 = 0.f; s.e1 = 0.f; s.e2 = 0.f;
    if (tx == 0 && xl) {
        if (!YEDGE || ym) s.e0 = p[-WW - 1];
        s.e1 = p[-1];
        if (!YEDGE || yp) s.e2 = p[WW - 1];
    } else if (tx == 31 && xr) {
        if (!YEDGE || ym) s.e0 = p[-WW + 4];
        s.e1 = p[4];
        if (!YEDGE || yp) s.e2 = p[WW + 4];
    }
}

// Build the 3x6 value window from a slot: interior x-halo via distance-2
// shuffles (paired-lane layout), edges from the prefetched scalars.
__device__ __forceinline__ void assemble(const Slot& s, int tx, float v[3][6])
{
    float4 m[3] = { s.m0, s.m1, s.m2 };
    float  e[3] = { s.e0, s.e1, s.e2 };
#pragma unroll
    for (int r = 0; r < 3; ++r) {
        v[r][1] = m[r].x; v[r][2] = m[r].y; v[r][3] = m[r].z; v[r][4] = m[r].w;
        const float lm = __shfl_up(m[r].w, 2);
        const float rm = __shfl_down(m[r].x, 2);
        v[r][0] = (tx == 0)  ? e[r] : lm;
        v[r][5] = (tx == 31) ? e[r] : rm;
    }
}

// Accumulators: 18 squares + 29 dots (E/W share: dotW[i] == dotE[i-1] == ew[i]).
struct Acc {
    float sq[3][6];
    float nw[4], nn[4], ne[4], sw[4], ss[4], se[4];
    float ew[5];
};

__device__ __forceinline__ void acc1(const float v[3][6], Acc& a)
{
#pragma unroll
    for (int r = 0; r < 3; ++r)
#pragma unroll
        for (int j = 0; j < 6; ++j) a.sq[r][j] = fmaf(v[r][j], v[r][j], a.sq[r][j]);
#pragma unroll
    for (int i = 0; i < 4; ++i) {
        const float c = v[1][i + 1];
        a.nw[i] = fmaf(c, v[0][i],     a.nw[i]);
        a.nn[i] = fmaf(c, v[0][i + 1], a.nn[i]);
        a.ne[i] = fmaf(c, v[0][i + 2], a.ne[i]);
        a.sw[i] = fmaf(c, v[2][i],     a.sw[i]);
        a.ss[i] = fmaf(c, v[2][i + 1], a.ss[i]);
        a.se[i] = fmaf(c, v[2][i + 2], a.se[i]);
    }
#pragma unroll
    for (int j = 0; j < 5; ++j) a.ew[j] = fmaf(v[1][j], v[1][j + 1], a.ew[j]);
}

__device__ __forceinline__ void merge(Acc& a)
{
#pragma unroll
    for (int r = 0; r < 3; ++r)
#pragma unroll
        for (int j = 0; j < 6; ++j) a.sq[r][j] += __shfl_xor(a.sq[r][j], 1);
#pragma unroll
    for (int i = 0; i < 4; ++i) {
        a.nw[i] += __shfl_xor(a.nw[i], 1);
        a.nn[i] += __shfl_xor(a.nn[i], 1);
        a.ne[i] += __shfl_xor(a.ne[i], 1);
        a.sw[i] += __shfl_xor(a.sw[i], 1);
        a.ss[i] += __shfl_xor(a.ss[i], 1);
        a.se[i] += __shfl_xor(a.se[i], 1);
    }
#pragma unroll
    for (int j = 0; j < 5; ++j) a.ew[j] += __shfl_xor(a.ew[j], 1);
}

// Weighted neighbor average for one channel + store.
__device__ __forceinline__ void acc2_store(const float v[3][6], const float w[8][4],
                                           float* __restrict__ op)
{
    float o[4];
#pragma unroll
    for (int i = 0; i < 4; ++i) {
        o[i] =      w[0][i] * v[0][i];
        o[i] = fmaf(w[1][i], v[0][i + 1], o[i]);
        o[i] = fmaf(w[2][i], v[0][i + 2], o[i]);
        o[i] = fmaf(w[3][i], v[1][i],     o[i]);
        o[i] = fmaf(w[4][i], v[1][i + 2], o[i]);
        o[i] = fmaf(w[5][i], v[2][i],     o[i]);
        o[i] = fmaf(w[6][i], v[2][i + 1], o[i]);
        o[i] = fmaf(w[7][i], v[2][i + 2], o[i]);
    }
    float4 ov = { o[0], o[1], o[2], o[3] };
    *reinterpret_cast<float4*>(op) = ov;
}

template <bool YEDGE, bool COMPUTE_NEXT>
__device__ __forceinline__ void step_body(const float* __restrict__ base,
                                          float* __restrict__ outp,
                                          float* __restrict__ simp,
                                          bool ym, bool yp, bool xl, bool xr,
                                          int tx, int half)
{
    Acc a;
#pragma unroll
    for (int r = 0; r < 3; ++r)
#pragma unroll
        for (int j = 0; j < 6; ++j) a.sq[r][j] = 0.f;
#pragma unroll
    for (int i = 0; i < 4; ++i) {
        a.nw[i] = 0.f; a.nn[i] = 0.f; a.ne[i] = 0.f;
        a.sw[i] = 0.f; a.ss[i] = 0.f; a.se[i] = 0.f;
    }
#pragma unroll
    for (int j = 0; j < 5; ++j) a.ew[j] = 0.f;

    Slot sA, sB, sC, sD;
    float v[3][6];

    // ---- Pass 1: distance-3 prefetch pipeline over NCH=16 channels ----
    load_slot<YEDGE>(sA, base + 0 * HWSZ, ym, yp, xl, xr, tx);
    load_slot<YEDGE>(sB, base + 1 * HWSZ, ym, yp, xl, xr, tx);
    load_slot<YEDGE>(sC, base + 2 * HWSZ, ym, yp, xl, xr, tx);
#pragma unroll 1
    for (int c = 0; c < NCH - 4; c += 4) {
        load_slot<YEDGE>(sD, base + (c + 3) * HWSZ, ym, yp, xl, xr, tx);
        assemble(sA, tx, v); acc1(v, a);
        load_slot<YEDGE>(sA, base + (c + 4) * HWSZ, ym, yp, xl, xr, tx);
        assemble(sB, tx, v); acc1(v, a);
        load_slot<YEDGE>(sB, base + (c + 5) * HWSZ, ym, yp, xl, xr, tx);
        assemble(sC, tx, v); acc1(v, a);
        load_slot<YEDGE>(sC, base + (c + 6) * HWSZ, ym, yp, xl, xr, tx);
        assemble(sD, tx, v); acc1(v, a);
    }
    // tail: channels NCH-4 .. NCH-1, no further prefetch
    load_slot<YEDGE>(sD, base + (NCH - 1) * HWSZ, ym, yp, xl, xr, tx);
    assemble(sA, tx, v); acc1(v, a);
    assemble(sB, tx, v); acc1(v, a);
    assemble(sC, tx, v); acc1(v, a);
    assemble(sD, tx, v); acc1(v, a);

    merge(a);

    float nrm[3][6];
#pragma unroll
    for (int r = 0; r < 3; ++r)
#pragma unroll
        for (int j = 0; j < 6; ++j) nrm[r][j] = __builtin_amdgcn_sqrtf(a.sq[r][j]);

    const bool r0 = !YEDGE || ym;
    const bool r2 = !YEDGE || yp;

    float w[8][4];
    float simarr[4];
#pragma unroll
    for (int i = 0; i < 4; ++i) {
        const bool cl = (i == 0) ? xl : true;   // colok[i]
        const bool cr = (i == 3) ? xr : true;   // colok[i+2]
        const float num[8] = { a.nw[i], a.nn[i], a.ne[i], a.ew[i], a.ew[i + 1],
                               a.sw[i], a.ss[i], a.se[i] };
        const float den[8] = { nrm[0][i], nrm[0][i + 1], nrm[0][i + 2],
                               nrm[1][i], nrm[1][i + 2],
                               nrm[2][i], nrm[2][i + 1], nrm[2][i + 2] };
        const bool  msk[8] = { r0 && cl, r0, r0 && cr,
                               cl, cr,
                               r2 && cl, r2, r2 && cr };
        const float cn = nrm[1][i + 1];
        float s[8];
        float tot = 0.f, cnt = 0.f;
#pragma unroll
        for (int d = 0; d < 8; ++d) {
            const float dn = fmaxf(cn * den[d], EPSV);
            const float cs = num[d] * __builtin_amdgcn_rcpf(dn);
            s[d] = msk[d] ? cs : 0.f;
            tot += s[d];
            cnt += msk[d] ? 1.f : 0.f;
        }
        simarr[i] = tot * __builtin_amdgcn_rcpf(cnt);
        if (COMPUTE_NEXT) {
            const float mx = fmaxf(fmaxf(fmaxf(s[0], s[1]), fmaxf(s[2], s[3])),
                                   fmaxf(fmaxf(s[4], s[5]), fmaxf(s[6], s[7])));
            float wsum = 0.f;
#pragma unroll
            for (int d = 0; d < 8; ++d) { w[d][i] = __expf(s[d] - mx); wsum += w[d][i]; }
            const float inv = __builtin_amdgcn_rcpf(wsum);
#pragma unroll
            for (int d = 0; d < 8; ++d) w[d][i] *= inv;
        }
    }
    if (half == 0) {
        float4 sv = { simarr[0], simarr[1], simarr[2], simarr[3] };
        *reinterpret_cast<float4*>(simp) = sv;
    }

    // ---- Pass 2: weighted neighbor average, same pipeline ----
    if (COMPUTE_NEXT) {
        load_slot<YEDGE>(sA, base + 0 * HWSZ, ym, yp, xl, xr, tx);
        load_slot<YEDGE>(sB, base + 1 * HWSZ, ym, yp, xl, xr, tx);
        load_slot<YEDGE>(sC, base + 2 * HWSZ, ym, yp, xl, xr, tx);
#pragma unroll 1
        for (int c = 0; c < NCH - 4; c += 4) {
            load_slot<YEDGE>(sD, base + (c + 3) * HWSZ, ym, yp, xl, xr, tx);
            assemble(sA, tx, v); acc2_store(v, w, outp + (c + 0) * HWSZ);
            load_slot<YEDGE>(sA, base + (c + 4) * HWSZ, ym, yp, xl, xr, tx);
            assemble(sB, tx, v); acc2_store(v, w, outp + (c + 1) * HWSZ);
            load_slot<YEDGE>(sB, base + (c + 5) * HWSZ, ym, yp, xl, xr, tx);
            assemble(sC, tx, v); acc2_store(v, w, outp + (c + 2) * HWSZ);
            load_slot<YEDGE>(sC, base + (c + 6) * HWSZ, ym, yp, xl, xr, tx);
            assemble(sD, tx, v); acc2_store(v, w, outp + (c + 3) * HWSZ);
        }
        load_slot<YEDGE>(sD, base + (NCH - 1) * HWSZ, ym, yp, xl, xr, tx);
        assemble(sA, tx, v); acc2_store(v, w, outp + (NCH - 4) * HWSZ);
        assemble(sB, tx, v); acc2_store(v, w, outp + (NCH - 3) * HWSZ);
        assemble(sC, tx, v); acc2_store(v, w, outp + (NCH - 2) * HWSZ);
        assemble(sD, tx, v); acc2_store(v, w, outp + (NCH - 1) * HWSZ);
    }
}

// Lane pairing (R3 structure): lane&1 = channel half (16 ch), lane>>1 = px
// group (4 px). Wave = 128 px (half row); block = 4 waves = 2 rows.
template <bool COMPUTE_NEXT>
__global__ __launch_bounds__(256, 4) void step_kernel(const float* __restrict__ F,
                                                      float* __restrict__ Fn,
                                                      float* __restrict__ simout)
{
    // Bijective XCD remap: 1024 blocks, each XCD owns one image.
    const int linear = blockIdx.y * (HH / 2) + blockIdx.x;   // 0..1023
    const int remap  = (linear & 7) * 128 + (linear >> 3);
    const int b      = remap >> 7;
    const int rowblk = remap & 127;

    const int tid  = threadIdx.x;
    const int wave = tid >> 6;
    const int lane = tid & 63;
    const int half = lane & 1;
    const int tx   = lane >> 1;            // 0..31
    const int y    = rowblk * 2 + (wave >> 1);
    const int x0   = (wave & 1) * 128 + (tx << 2);
    const int c0   = half * NCH;

    const bool ym = y > 0, yp = y < HH - 1;
    const bool xl = x0 > 0, xr = x0 < WW - 4;

    const float* base = F + (size_t)b * IMGSZ + (size_t)c0 * HWSZ + y * WW + x0;
    float* outp = Fn ? (Fn + (size_t)b * IMGSZ + (size_t)c0 * HWSZ + y * WW + x0) : nullptr;
    float* simp = simout + b * HWSZ + y * WW + x0;

    if (ym && yp) step_body<false, COMPUTE_NEXT>(base, outp, simp, ym, yp, xl, xr, tx, half);
    else          step_body<true,  COMPUTE_NEXT>(base, outp, simp, ym, yp, xl, xr, tx, half);
}

// out[g][t][p] = 0.25 * sum_{i<4} sims[tt][4g+i][p], tt = {0,0,1,2}[t]
__global__ __launch_bounds__(256) void reduce_kernel(const float* __restrict__ sims,
                                                     float* __restrict__ out)
{
    const int idx = blockIdx.x * blockDim.x + threadIdx.x;  // 131072 float4s
    const int p4 = idx & (HWSZ / 4 - 1);
    const int t  = (idx >> 14) & 3;
    const int g  = idx >> 16;
    const int tt = (t <= 1) ? 0 : (t - 1);
    const float4* s = reinterpret_cast<const float4*>(sims) +
                      (size_t)(tt * NIMG + g * 4) * (HWSZ / 4) + p4;
    float4 a = s[0];
    float4 b = s[HWSZ / 4];
    float4 c = s[2 * (HWSZ / 4)];
    float4 d = s[3 * (HWSZ / 4)];
    float4 o;
    o.x = 0.25f * (a.x + b.x + c.x + d.x);
    o.y = 0.25f * (a.y + b.y + c.y + d.y);
    o.z = 0.25f * (a.z + b.z + c.z + d.z);
    o.w = 0.25f * (a.w + b.w + c.w + d.w);
    reinterpret_cast<float4*>(out)[idx] = o;
}

extern "C" void kernel_launch(void* const* d_in, const int* in_sizes, int n_in,
                              void* d_out, int out_size, void* d_ws, size_t ws_size,
                              hipStream_t stream)
{
    const float* F0 = (const float*)d_in[0];
    float* F1   = (float*)d_ws;                       // 64 MB
    float* F2   = F1 + (size_t)NIMG * IMGSZ;          // 64 MB
    float* sims = F2 + (size_t)NIMG * IMGSZ;          // 6 MB

    dim3 block(256);
    dim3 grid(HH / 2, NIMG);

    hipLaunchKernelGGL((step_kernel<true>),  grid, block, 0, stream, F0, F1, sims);
    hipLaunchKernelGGL((step_kernel<true>),  grid, block, 0, stream, F1, F2, sims + (size_t)NIMG * HWSZ);
    hipLaunchKernelGGL((step_kernel<false>), grid, block, 0, stream, F2, nullptr, sims + (size_t)2 * NIMG * HWSZ);

    hipLaunchKernelGGL(reduce_kernel, dim3((2 * 4 * HWSZ / 4) / 256), block, 0, stream,
                       sims, (float*)d_out);
}

// Round 7
// 407.096 us; speedup vs baseline: 1.8095x; 1.8095x over previous
//
#include <hip/hip_runtime.h>

#define HH 256
#define WW 256
#define CC 32
#define HWSZ (HH * WW)
#define IMGSZ (CC * HWSZ)
#define NIMG 8
#define EPSV 1e-8f
#define NCH (CC / 2)   // channels per lane (2-way channel split)

// Halo for one channel around this lane's 4 px. Interior x-halo comes from the
// paired-lane-aware shuffle (distance 2: same channel-half, previous px group);
// only tx==0/tx==31 lanes fall back to a predicated scalar load.
__device__ __forceinline__ void load_halo_sh(const float* __restrict__ p,
                                             bool ym, bool yp, bool xl, bool xr,
                                             int tx, float v[3][6])
{
    const bool rowok[3] = { ym, true, yp };
#pragma unroll
    for (int r = 0; r < 3; ++r) {
        const float* row = p + (r - 1) * WW;
        float4 m;
        if (rowok[r]) m = *reinterpret_cast<const float4*>(row);
        else { m.x = m.y = m.z = m.w = 0.f; }
        v[r][1] = m.x; v[r][2] = m.y; v[r][3] = m.z; v[r][4] = m.w;
        float lm = __shfl_up(m.w, 2);
        float rm = __shfl_down(m.x, 2);
        if (tx == 0)  lm = (xl && rowok[r]) ? row[-1] : 0.f;
        if (tx == 31) rm = (xr && rowok[r]) ? row[4]  : 0.f;
        v[r][0] = lm;
        v[r][5] = rm;
    }
}

__device__ __forceinline__ void acc_pass1(const float v[3][6],
                                          float sq[3][6], float dotv[8][4])
{
#pragma unroll
    for (int r = 0; r < 3; ++r)
#pragma unroll
        for (int j = 0; j < 6; ++j) sq[r][j] = fmaf(v[r][j], v[r][j], sq[r][j]);
    int d = 0;
#pragma unroll
    for (int dyi = 0; dyi < 3; ++dyi)
#pragma unroll
        for (int dxi = 0; dxi < 3; ++dxi) {
            if (dyi == 1 && dxi == 1) continue;
#pragma unroll
            for (int i = 0; i < 4; ++i)
                dotv[d][i] = fmaf(v[1][i + 1], v[dyi][i + dxi], dotv[d][i]);
            ++d;
        }
}

__device__ __forceinline__ void acc_pass2(const float v[3][6],
                                          const float w[8][4], float o[4])
{
    int d = 0;
#pragma unroll
    for (int dyi = 0; dyi < 3; ++dyi)
#pragma unroll
        for (int dxi = 0; dxi < 3; ++dxi) {
            if (dyi == 1 && dxi == 1) continue;
#pragma unroll
            for (int i = 0; i < 4; ++i)
                o[i] = fmaf(w[d][i], v[dyi][i + dxi], o[i]);
            ++d;
        }
}

// Lane pairing: lane&1 selects channel half (16 channels each), lane>>1 selects
// the 4-px group. A wave covers 128 px (half a row); a block = 4 waves = 2 rows.
template <bool COMPUTE_NEXT>
__global__ __launch_bounds__(256, 4) void step_kernel(const float* __restrict__ F,
                                                      float* __restrict__ Fn,
                                                      float* __restrict__ simout)
{
    // Bijective XCD remap: 1024 blocks, each XCD gets one image's 128 row-blocks.
    const int linear = blockIdx.y * (HH / 2) + blockIdx.x;   // 0..1023
    const int remap  = (linear & 7) * 128 + (linear >> 3);
    const int b      = remap >> 7;
    const int rowblk = remap & 127;

    const int tid  = threadIdx.x;
    const int wave = tid >> 6;
    const int lane = tid & 63;
    const int half = lane & 1;
    const int tx   = lane >> 1;            // 0..31
    const int y    = rowblk * 2 + (wave >> 1);
    const int x0   = (wave & 1) * 128 + (tx << 2);
    const int c0   = half * NCH;

    const bool ym = y > 0, yp = y < HH - 1;
    const bool xl = x0 > 0, xr = x0 < WW - 4;
    const bool rowok[3] = { ym, true, yp };
    const bool colok[6] = { xl, true, true, true, true, xr };

    const float* base = F + (size_t)b * IMGSZ + (size_t)c0 * HWSZ + y * WW + x0;

    // ---------------- Pass 1: partial norms + dots over 16 channels ----------
    float sq[3][6];
    float dotv[8][4];
#pragma unroll
    for (int r = 0; r < 3; ++r)
#pragma unroll
        for (int j = 0; j < 6; ++j) sq[r][j] = 0.f;
#pragma unroll
    for (int d = 0; d < 8; ++d)
#pragma unroll
        for (int i = 0; i < 4; ++i) dotv[d][i] = 0.f;

    {
        // Depth-2 prefetch: 3 rotating buffers of the R3-proven v[3][6] type.
        float va[3][6], vb[3][6], vc[3][6];
        load_halo_sh(base + 0 * HWSZ, ym, yp, xl, xr, tx, va);
        load_halo_sh(base + 1 * HWSZ, ym, yp, xl, xr, tx, vb);
#pragma unroll 1
        for (int c = 0; c < NCH - 6; c += 3) {   // c = 0,3,6,9
            load_halo_sh(base + (c + 2) * HWSZ, ym, yp, xl, xr, tx, vc);
            acc_pass1(va, sq, dotv);
            load_halo_sh(base + (c + 3) * HWSZ, ym, yp, xl, xr, tx, va);
            acc_pass1(vb, sq, dotv);
            load_halo_sh(base + (c + 4) * HWSZ, ym, yp, xl, xr, tx, vb);
            acc_pass1(vc, sq, dotv);
        }
        // tail: va=ch12, vb=ch13; load 14,15 and drain.
        load_halo_sh(base + (NCH - 2) * HWSZ, ym, yp, xl, xr, tx, vc);
        acc_pass1(va, sq, dotv);
        load_halo_sh(base + (NCH - 1) * HWSZ, ym, yp, xl, xr, tx, va);
        acc_pass1(vb, sq, dotv);
        acc_pass1(vc, sq, dotv);
        acc_pass1(va, sq, dotv);
    }

    // Merge the two channel halves (paired lanes).
#pragma unroll
    for (int r = 0; r < 3; ++r)
#pragma unroll
        for (int j = 0; j < 6; ++j) sq[r][j] += __shfl_xor(sq[r][j], 1);
#pragma unroll
    for (int d = 0; d < 8; ++d)
#pragma unroll
        for (int i = 0; i < 4; ++i) dotv[d][i] += __shfl_xor(dotv[d][i], 1);

    float nrm[3][6];
#pragma unroll
    for (int r = 0; r < 3; ++r)
#pragma unroll
        for (int j = 0; j < 6; ++j) nrm[r][j] = sqrtf(sq[r][j]);

    float w[8][4];
    float simarr[4];
#pragma unroll
    for (int i = 0; i < 4; ++i) {
        float s[8];
        const float cn = nrm[1][i + 1];
        float tot = 0.f, cnt = 0.f;
        int d = 0;
#pragma unroll
        for (int dyi = 0; dyi < 3; ++dyi)
#pragma unroll
            for (int dxi = 0; dxi < 3; ++dxi) {
                if (dyi == 1 && dxi == 1) continue;
                const bool m = rowok[dyi] && colok[i + dxi];
                const float den = fmaxf(cn * nrm[dyi][i + dxi], EPSV);
                const float cs = dotv[d][i] / den;
                s[d] = m ? cs : 0.f;
                tot += s[d];
                cnt += m ? 1.f : 0.f;
                ++d;
            }
        simarr[i] = tot / cnt;
        if (COMPUTE_NEXT) {
            float mx = s[0];
#pragma unroll
            for (int d2 = 1; d2 < 8; ++d2) mx = fmaxf(mx, s[d2]);
            float wsum = 0.f;
#pragma unroll
            for (int d2 = 0; d2 < 8; ++d2) { w[d2][i] = __expf(s[d2] - mx); wsum += w[d2][i]; }
            const float inv = 1.f / wsum;
#pragma unroll
            for (int d2 = 0; d2 < 8; ++d2) w[d2][i] *= inv;
        }
    }
    if (half == 0) {
        float4 simv = { simarr[0], simarr[1], simarr[2], simarr[3] };
        *reinterpret_cast<float4*>(simout + b * HWSZ + y * WW + x0) = simv;
    }

    // ---------------- Pass 2: weighted neighbor average (own 16 channels) ----
    if (COMPUTE_NEXT) {
        float* outp = Fn + (size_t)b * IMGSZ + (size_t)c0 * HWSZ + y * WW + x0;
        float va[3][6], vb[3][6], vc[3][6];
        load_halo_sh(base + 0 * HWSZ, ym, yp, xl, xr, tx, va);
        load_halo_sh(base + 1 * HWSZ, ym, yp, xl, xr, tx, vb);
#pragma unroll 1
        for (int c = 0; c < NCH - 6; c += 3) {   // c = 0,3,6,9
            load_halo_sh(base + (c + 2) * HWSZ, ym, yp, xl, xr, tx, vc);
            {
                float o[4] = { 0.f, 0.f, 0.f, 0.f };
                acc_pass2(va, w, o);
                float4 ov = { o[0], o[1], o[2], o[3] };
                *reinterpret_cast<float4*>(outp + c * HWSZ) = ov;
            }
            load_halo_sh(base + (c + 3) * HWSZ, ym, yp, xl, xr, tx, va);
            {
                float o[4] = { 0.f, 0.f, 0.f, 0.f };
                acc_pass2(vb, w, o);
                float4 ov = { o[0], o[1], o[2], o[3] };
                *reinterpret_cast<float4*>(outp + (c + 1) * HWSZ) = ov;
            }
            load_halo_sh(base + (c + 4) * HWSZ, ym, yp, xl, xr, tx, vb);
            {
                float o[4] = { 0.f, 0.f, 0.f, 0.f };
                acc_pass2(vc, w, o);
                float4 ov = { o[0], o[1], o[2], o[3] };
                *reinterpret_cast<float4*>(outp + (c + 2) * HWSZ) = ov;
            }
        }
        load_halo_sh(base + (NCH - 2) * HWSZ, ym, yp, xl, xr, tx, vc);
        {
            float o[4] = { 0.f, 0.f, 0.f, 0.f };
            acc_pass2(va, w, o);
            float4 ov = { o[0], o[1], o[2], o[3] };
            *reinterpret_cast<float4*>(outp + (NCH - 4) * HWSZ) = ov;
        }
        load_halo_sh(base + (NCH - 1) * HWSZ, ym, yp, xl, xr, tx, va);
        {
            float o[4] = { 0.f, 0.f, 0.f, 0.f };
            acc_pass2(vb, w, o);
            float4 ov = { o[0], o[1], o[2], o[3] };
            *reinterpret_cast<float4*>(outp + (NCH - 3) * HWSZ) = ov;
        }
        {
            float o[4] = { 0.f, 0.f, 0.f, 0.f };
            acc_pass2(vc, w, o);
            float4 ov = { o[0], o[1], o[2], o[3] };
            *reinterpret_cast<float4*>(outp + (NCH - 2) * HWSZ) = ov;
        }
        {
            float o[4] = { 0.f, 0.f, 0.f, 0.f };
            acc_pass2(va, w, o);
            float4 ov = { o[0], o[1], o[2], o[3] };
            *reinterpret_cast<float4*>(outp + (NCH - 1) * HWSZ) = ov;
        }
    }
}

// out[g][t][p] = 0.25 * sum_{i<4} sims[tt][4g+i][p], tt = {0,0,1,2}[t]
__global__ __launch_bounds__(256) void reduce_kernel(const float* __restrict__ sims,
                                                     float* __restrict__ out)
{
    const int idx = blockIdx.x * blockDim.x + threadIdx.x;  // 131072 float4s
    const int p4 = idx & (HWSZ / 4 - 1);
    const int t  = (idx >> 14) & 3;
    const int g  = idx >> 16;
    const int tt = (t <= 1) ? 0 : (t - 1);
    const float4* s = reinterpret_cast<const float4*>(sims) +
                      (size_t)(tt * NIMG + g * 4) * (HWSZ / 4) + p4;
    float4 a = s[0];
    float4 b = s[HWSZ / 4];
    float4 c = s[2 * (HWSZ / 4)];
    float4 d = s[3 * (HWSZ / 4)];
    float4 o;
    o.x = 0.25f * (a.x + b.x + c.x + d.x);
    o.y = 0.25f * (a.y + b.y + c.y + d.y);
    o.z = 0.25f * (a.z + b.z + c.z + d.z);
    o.w = 0.25f * (a.w + b.w + c.w + d.w);
    reinterpret_cast<float4*>(out)[idx] = o;
}

extern "C" void kernel_launch(void* const* d_in, const int* in_sizes, int n_in,
                              void* d_out, int out_size, void* d_ws, size_t ws_size,
                              hipStream_t stream)
{
    const float* F0 = (const float*)d_in[0];
    float* F1   = (float*)d_ws;                       // 64 MB
    float* F2   = F1 + (size_t)NIMG * IMGSZ;          // 64 MB
    float* sims = F2 + (size_t)NIMG * IMGSZ;          // 6 MB

    dim3 block(256);
    dim3 grid(HH / 2, NIMG);

    hipLaunchKernelGGL((step_kernel<true>),  grid, block, 0, stream, F0, F1, sims);
    hipLaunchKernelGGL((step_kernel<true>),  grid, block, 0, stream, F1, F2, sims + (size_t)NIMG * HWSZ);
    hipLaunchKernelGGL((step_kernel<false>), grid, block, 0, stream, F2, nullptr, sims + (size_t)2 * NIMG * HWSZ);

    hipLaunchKernelGGL(reduce_kernel, dim3((2 * 4 * HWSZ / 4) / 256), block, 0, stream,
                       sims, (float*)d_out);
}

// Round 9
// 177.011 us; speedup vs baseline: 4.1616x; 2.2998x over previous
//
#include <hip/hip_runtime.h>

#define HH 256
#define WW 256
#define CC 32
#define HWSZ (HH * WW)
#define IMGSZ (CC * HWSZ)
#define NIMG 8
#define EPSV 1e-8f
#define NCH (CC / 2)   // channels per lane (2-way channel split)

__device__ __forceinline__ void acc_pass1(const float v[3][6],
                                          float sq[3][6], float dotv[8][4])
{
#pragma unroll
    for (int r = 0; r < 3; ++r)
#pragma unroll
        for (int j = 0; j < 6; ++j) sq[r][j] = fmaf(v[r][j], v[r][j], sq[r][j]);
    int d = 0;
#pragma unroll
    for (int dyi = 0; dyi < 3; ++dyi)
#pragma unroll
        for (int dxi = 0; dxi < 3; ++dxi) {
            if (dyi == 1 && dxi == 1) continue;
#pragma unroll
            for (int i = 0; i < 4; ++i)
                dotv[d][i] = fmaf(v[1][i + 1], v[dyi][i + dxi], dotv[d][i]);
            ++d;
        }
}

__device__ __forceinline__ void acc_pass2(const float v[3][6],
                                          const float w[8][4], float o[4])
{
    int d = 0;
#pragma unroll
    for (int dyi = 0; dyi < 3; ++dyi)
#pragma unroll
        for (int dxi = 0; dxi < 3; ++dxi) {
            if (dyi == 1 && dxi == 1) continue;
#pragma unroll
            for (int i = 0; i < 4; ++i)
                o[i] = fmaf(w[d][i], v[dyi][i + dxi], o[i]);
            ++d;
        }
}

// Depth-2 prefetch state per stage: 3 raw float4 rows (t/m/b) + 3 edge scalars,
// all DISCRETE named variables (no structs/arrays -> guaranteed SROA).
// Letter suffixes avoid the pp-number pasting trap (m##K##0.x -> "0.x" token).
#define DECLS(K) float4 m##K##t, m##K##m, m##K##b; float e##K##t, e##K##m, e##K##b;

#define LOADS(K, CIDX) { \
    const float* p_ = base + (CIDX) * HWSZ; \
    m##K##m = *reinterpret_cast<const float4*>(p_); \
    if (ym) m##K##t = *reinterpret_cast<const float4*>(p_ - WW); else m##K##t = z4; \
    if (yp) m##K##b = *reinterpret_cast<const float4*>(p_ + WW); else m##K##b = z4; \
    e##K##t = 0.f; e##K##m = 0.f; e##K##b = 0.f; \
    if (tx == 0) { \
        if (xl) { if (ym) e##K##t = p_[-WW - 1]; e##K##m = p_[-1]; if (yp) e##K##b = p_[WW - 1]; } \
    } else if (tx == 31) { \
        if (xr) { if (ym) e##K##t = p_[-WW + 4]; e##K##m = p_[4]; if (yp) e##K##b = p_[WW + 4]; } \
    } }

#define ASSEMBLE(K, VV) { \
    VV[0][1] = m##K##t.x; VV[0][2] = m##K##t.y; VV[0][3] = m##K##t.z; VV[0][4] = m##K##t.w; \
    VV[1][1] = m##K##m.x; VV[1][2] = m##K##m.y; VV[1][3] = m##K##m.z; VV[1][4] = m##K##m.w; \
    VV[2][1] = m##K##b.x; VV[2][2] = m##K##b.y; VV[2][3] = m##K##b.z; VV[2][4] = m##K##b.w; \
    const float lmt_ = __shfl_up(m##K##t.w, 2), rmt_ = __shfl_down(m##K##t.x, 2); \
    const float lmm_ = __shfl_up(m##K##m.w, 2), rmm_ = __shfl_down(m##K##m.x, 2); \
    const float lmb_ = __shfl_up(m##K##b.w, 2), rmb_ = __shfl_down(m##K##b.x, 2); \
    VV[0][0] = (tx == 0) ? e##K##t : lmt_;  VV[0][5] = (tx == 31) ? e##K##t : rmt_; \
    VV[1][0] = (tx == 0) ? e##K##m : lmm_;  VV[1][5] = (tx == 31) ? e##K##m : rmm_; \
    VV[2][0] = (tx == 0) ? e##K##b : lmb_;  VV[2][5] = (tx == 31) ? e##K##b : rmb_; }

#define ACC1(K) { float v_[3][6]; ASSEMBLE(K, v_); acc_pass1(v_, sq, dotv); }

#define ACC2(K, OFF) { float v_[3][6]; ASSEMBLE(K, v_); \
    float o_[4] = { 0.f, 0.f, 0.f, 0.f }; acc_pass2(v_, w, o_); \
    float4 ov_ = { o_[0], o_[1], o_[2], o_[3] }; \
    *reinterpret_cast<float4*>(outp + (OFF) * HWSZ) = ov_; }

// Lane pairing (R3): lane&1 = channel half (16 ch), lane>>1 = px group (4 px).
// Wave = 128 px (half row); block = 4 waves = 2 rows.
template <bool COMPUTE_NEXT>
__global__ __launch_bounds__(256, 3) void step_kernel(const float* __restrict__ F,
                                                      float* __restrict__ Fn,
                                                      float* __restrict__ simout)
{
    // Bijective XCD remap: 1024 blocks, each XCD owns one image.
    const int linear = blockIdx.y * (HH / 2) + blockIdx.x;   // 0..1023
    const int remap  = (linear & 7) * 128 + (linear >> 3);
    const int b      = remap >> 7;
    const int rowblk = remap & 127;

    const int tid  = threadIdx.x;
    const int wave = tid >> 6;
    const int lane = tid & 63;
    const int half = lane & 1;
    const int tx   = lane >> 1;            // 0..31
    const int y    = rowblk * 2 + (wave >> 1);
    const int x0   = (wave & 1) * 128 + (tx << 2);
    const int c0   = half * NCH;

    const bool ym = y > 0, yp = y < HH - 1;
    const bool xl = x0 > 0, xr = x0 < WW - 4;
    const bool rowok[3] = { ym, true, yp };
    const bool colok[6] = { xl, true, true, true, true, xr };

    const float* base = F + (size_t)b * IMGSZ + (size_t)c0 * HWSZ + y * WW + x0;
    float4 z4; z4.x = z4.y = z4.z = z4.w = 0.f;

    // ---------------- Pass 1: partial norms + dots over 16 channels ----------
    float sq[3][6];
    float dotv[8][4];
#pragma unroll
    for (int r = 0; r < 3; ++r)
#pragma unroll
        for (int j = 0; j < 6; ++j) sq[r][j] = 0.f;
#pragma unroll
    for (int d = 0; d < 8; ++d)
#pragma unroll
        for (int i = 0; i < 4; ++i) dotv[d][i] = 0.f;

    {
        DECLS(A) DECLS(B) DECLS(C)
        LOADS(A, 0) LOADS(B, 1)
#pragma unroll 1
        for (int c = 0; c < NCH - 6; c += 3) {   // c = 0,3,6,9 -> ch 0..11
            LOADS(C, c + 2) ACC1(A)
            LOADS(A, c + 3) ACC1(B)
            LOADS(B, c + 4) ACC1(C)
        }
        // A=ch12, B=ch13 loaded; remaining 12..15
        LOADS(C, NCH - 2) ACC1(A)
        LOADS(A, NCH - 1) ACC1(B)
        ACC1(C)
        ACC1(A)
    }

    // Merge the two channel halves (paired lanes).
#pragma unroll
    for (int r = 0; r < 3; ++r)
#pragma unroll
        for (int j = 0; j < 6; ++j) sq[r][j] += __shfl_xor(sq[r][j], 1);
#pragma unroll
    for (int d = 0; d < 8; ++d)
#pragma unroll
        for (int i = 0; i < 4; ++i) dotv[d][i] += __shfl_xor(dotv[d][i], 1);

    float nrm[3][6];
#pragma unroll
    for (int r = 0; r < 3; ++r)
#pragma unroll
        for (int j = 0; j < 6; ++j) nrm[r][j] = sqrtf(sq[r][j]);

    float w[8][4];
    float simarr[4];
#pragma unroll
    for (int i = 0; i < 4; ++i) {
        float s[8];
        const float cn = nrm[1][i + 1];
        float tot = 0.f, cnt = 0.f;
        int d = 0;
#pragma unroll
        for (int dyi = 0; dyi < 3; ++dyi)
#pragma unroll
            for (int dxi = 0; dxi < 3; ++dxi) {
                if (dyi == 1 && dxi == 1) continue;
                const bool m = rowok[dyi] && colok[i + dxi];
                const float den = fmaxf(cn * nrm[dyi][i + dxi], EPSV);
                const float cs = dotv[d][i] / den;
                s[d] = m ? cs : 0.f;
                tot += s[d];
                cnt += m ? 1.f : 0.f;
                ++d;
            }
        simarr[i] = tot / cnt;
        if (COMPUTE_NEXT) {
            float mx = s[0];
#pragma unroll
            for (int d2 = 1; d2 < 8; ++d2) mx = fmaxf(mx, s[d2]);
            float wsum = 0.f;
#pragma unroll
            for (int d2 = 0; d2 < 8; ++d2) { w[d2][i] = __expf(s[d2] - mx); wsum += w[d2][i]; }
            const float inv = 1.f / wsum;
#pragma unroll
            for (int d2 = 0; d2 < 8; ++d2) w[d2][i] *= inv;
        }
    }
    if (half == 0) {
        float4 simv = { simarr[0], simarr[1], simarr[2], simarr[3] };
        *reinterpret_cast<float4*>(simout + b * HWSZ + y * WW + x0) = simv;
    }

    // ---------------- Pass 2: weighted neighbor average (own 16 channels) ----
    if (COMPUTE_NEXT) {
        float* outp = Fn + (size_t)b * IMGSZ + (size_t)c0 * HWSZ + y * WW + x0;
        DECLS(A) DECLS(B) DECLS(C)
        LOADS(A, 0) LOADS(B, 1)
#pragma unroll 1
        for (int c = 0; c < NCH - 6; c += 3) {   // c = 0,3,6,9
            LOADS(C, c + 2) ACC2(A, c + 0)
            LOADS(A, c + 3) ACC2(B, c + 1)
            LOADS(B, c + 4) ACC2(C, c + 2)
        }
        LOADS(C, NCH - 2) ACC2(A, NCH - 4)
        LOADS(A, NCH - 1) ACC2(B, NCH - 3)
        ACC2(C, NCH - 2)
        ACC2(A, NCH - 1)
    }
}

// out[g][t][p] = 0.25 * sum_{i<4} sims[tt][4g+i][p], tt = {0,0,1,2}[t]
__global__ __launch_bounds__(256) void reduce_kernel(const float* __restrict__ sims,
                                                     float* __restrict__ out)
{
    const int idx = blockIdx.x * blockDim.x + threadIdx.x;  // 131072 float4s
    const int p4 = idx & (HWSZ / 4 - 1);
    const int t  = (idx >> 14) & 3;
    const int g  = idx >> 16;
    const int tt = (t <= 1) ? 0 : (t - 1);
    const float4* s = reinterpret_cast<const float4*>(sims) +
                      (size_t)(tt * NIMG + g * 4) * (HWSZ / 4) + p4;
    float4 a = s[0];
    float4 b = s[HWSZ / 4];
    float4 c = s[2 * (HWSZ / 4)];
    float4 d = s[3 * (HWSZ / 4)];
    float4 o;
    o.x = 0.25f * (a.x + b.x + c.x + d.x);
    o.y = 0.25f * (a.y + b.y + c.y + d.y);
    o.z = 0.25f * (a.z + b.z + c.z + d.z);
    o.w = 0.25f * (a.w + b.w + c.w + d.w);
    reinterpret_cast<float4*>(out)[idx] = o;
}

extern "C" void kernel_launch(void* const* d_in, const int* in_sizes, int n_in,
                              void* d_out, int out_size, void* d_ws, size_t ws_size,
                              hipStream_t stream)
{
    const float* F0 = (const float*)d_in[0];
    float* F1   = (float*)d_ws;                       // 64 MB
    float* F2   = F1 + (size_t)NIMG * IMGSZ;          // 64 MB
    float* sims = F2 + (size_t)NIMG * IMGSZ;          // 6 MB

    dim3 block(256);
    dim3 grid(HH / 2, NIMG);

    hipLaunchKernelGGL((step_kernel<true>),  grid, block, 0, stream, F0, F1, sims);
    hipLaunchKernelGGL((step_kernel<true>),  grid, block, 0, stream, F1, F2, sims + (size_t)NIMG * HWSZ);
    hipLaunchKernelGGL((step_kernel<false>), grid, block, 0, stream, F2, nullptr, sims + (size_t)2 * NIMG * HWSZ);

    hipLaunchKernelGGL(reduce_kernel, dim3((2 * 4 * HWSZ / 4) / 256), block, 0, stream,
                       sims, (float*)d_out);
}

// Round 10
// 175.471 us; speedup vs baseline: 4.1982x; 1.0088x over previous
//
#include <hip/hip_runtime.h>

#define HH 256
#define WW 256
#define CC 32
#define HWSZ (HH * WW)
#define IMGSZ (CC * HWSZ)
#define NIMG 8
#define EPSV 1e-8f
#define NCH (CC / 2)   // channels per lane (2-way channel split)

// Halo for one channel around this lane's 4 px. Interior x-halo via paired-lane
// shuffle (distance 2); mid-row boundary columns (127/128) come from the
// 1 KB LDS edge cache staged once at kernel start (broadcast ds_read, ~free).
// eg points at lds_edge[ch][wv]; eg[r*2+0] = col 127, eg[r*2+1] = col 128 of
// absolute row y + r - 1.
__device__ __forceinline__ void load_halo_sh(const float* __restrict__ p,
                                             bool ym, bool yp, bool xl, bool xr,
                                             int tx, const float* eg, float v[3][6])
{
    const bool rowok[3] = { ym, true, yp };
#pragma unroll
    for (int r = 0; r < 3; ++r) {
        const float* row = p + (r - 1) * WW;
        float4 m;
        if (rowok[r]) m = *reinterpret_cast<const float4*>(row);
        else { m.x = m.y = m.z = m.w = 0.f; }
        v[r][1] = m.x; v[r][2] = m.y; v[r][3] = m.z; v[r][4] = m.w;
        const float lm = __shfl_up(m.w, 2);
        const float rm = __shfl_down(m.x, 2);
        const float el = (xl && rowok[r]) ? eg[r * 2 + 0] : 0.f;  // col 127
        const float er = (xr && rowok[r]) ? eg[r * 2 + 1] : 0.f;  // col 128
        v[r][0] = (tx == 0)  ? el : lm;
        v[r][5] = (tx == 31) ? er : rm;
    }
}

__device__ __forceinline__ void acc_pass1(const float v[3][6],
                                          float sq[3][6], float dotv[8][4])
{
#pragma unroll
    for (int r = 0; r < 3; ++r)
#pragma unroll
        for (int j = 0; j < 6; ++j) sq[r][j] = fmaf(v[r][j], v[r][j], sq[r][j]);
    int d = 0;
#pragma unroll
    for (int dyi = 0; dyi < 3; ++dyi)
#pragma unroll
        for (int dxi = 0; dxi < 3; ++dxi) {
            if (dyi == 1 && dxi == 1) continue;
#pragma unroll
            for (int i = 0; i < 4; ++i)
                dotv[d][i] = fmaf(v[1][i + 1], v[dyi][i + dxi], dotv[d][i]);
            ++d;
        }
}

__device__ __forceinline__ void acc_pass2(const float v[3][6],
                                          const float w[8][4], float o[4])
{
    int d = 0;
#pragma unroll
    for (int dyi = 0; dyi < 3; ++dyi)
#pragma unroll
        for (int dxi = 0; dxi < 3; ++dxi) {
            if (dyi == 1 && dxi == 1) continue;
#pragma unroll
            for (int i = 0; i < 4; ++i)
                o[i] = fmaf(w[d][i], v[dyi][i + dxi], o[i]);
            ++d;
        }
}

// Lane pairing (R3): lane&1 = channel half (16 ch), lane>>1 = px group (4 px).
// Wave = 128 px (half row); block = 4 waves = 2 rows.
template <bool COMPUTE_NEXT>
__global__ __launch_bounds__(256, 4) void step_kernel(const float* __restrict__ F,
                                                      float* __restrict__ Fn,
                                                      float* __restrict__ simout)
{
    // Bijective XCD remap: 1024 blocks, each XCD owns one image.
    const int linear = blockIdx.y * (HH / 2) + blockIdx.x;   // 0..1023
    const int remap  = (linear & 7) * 128 + (linear >> 3);
    const int b      = remap >> 7;
    const int rowblk = remap & 127;

    const int tid  = threadIdx.x;
    const int wave = tid >> 6;
    const int lane = tid & 63;
    const int half = lane & 1;
    const int tx   = lane >> 1;            // 0..31
    const int y0   = rowblk * 2;
    const int wv   = wave >> 1;            // which of the 2 block rows
    const int y    = y0 + wv;
    const int x0   = (wave & 1) * 128 + (tx << 2);
    const int c0   = half * NCH;

    // ---- Edge-column cache: cols 127/128 of rows y0-1..y0+2, all 32 ch ----
    __shared__ float lds_edge[CC][4][2];   // 1 KB
    {
        const int ch = tid >> 3;           // 0..31
        const int rw = (tid >> 1) & 3;     // 0..3  -> absolute row y0-1+rw
        const int sd = tid & 1;            // 0: col 127, 1: col 128
        int arow = y0 - 1 + rw;
        arow = arow < 0 ? 0 : (arow > HH - 1 ? HH - 1 : arow);
        lds_edge[ch][rw][sd] =
            F[(size_t)b * IMGSZ + (size_t)ch * HWSZ + arow * WW + 127 + sd];
    }
    __syncthreads();

    const bool ym = y > 0, yp = y < HH - 1;
    const bool xl = x0 > 0, xr = x0 < WW - 4;
    const bool rowok[3] = { ym, true, yp };
    const bool colok[6] = { xl, true, true, true, true, xr };

    const float* base = F + (size_t)b * IMGSZ + (size_t)c0 * HWSZ + y * WW + x0;
    const float* egbase = &lds_edge[c0][wv][0];   // + cidx*8 per channel

    // ---------------- Pass 1: partial norms + dots over 16 channels ----------
    float sq[3][6];
    float dotv[8][4];
#pragma unroll
    for (int r = 0; r < 3; ++r)
#pragma unroll
        for (int j = 0; j < 6; ++j) sq[r][j] = 0.f;
#pragma unroll
    for (int d = 0; d < 8; ++d)
#pragma unroll
        for (int i = 0; i < 4; ++i) dotv[d][i] = 0.f;

    {
        float va[3][6], vb[3][6];
        load_halo_sh(base, ym, yp, xl, xr, tx, egbase, va);
        for (int c = 0; c < NCH; c += 2) {
            load_halo_sh(base + (c + 1) * HWSZ, ym, yp, xl, xr, tx,
                         egbase + (c + 1) * 8, vb);
            acc_pass1(va, sq, dotv);
            if (c + 2 < NCH) load_halo_sh(base + (c + 2) * HWSZ, ym, yp, xl, xr, tx,
                                          egbase + (c + 2) * 8, va);
            acc_pass1(vb, sq, dotv);
        }
    }

    // Merge the two channel halves (paired lanes).
#pragma unroll
    for (int r = 0; r < 3; ++r)
#pragma unroll
        for (int j = 0; j < 6; ++j) sq[r][j] += __shfl_xor(sq[r][j], 1);
#pragma unroll
    for (int d = 0; d < 8; ++d)
#pragma unroll
        for (int i = 0; i < 4; ++i) dotv[d][i] += __shfl_xor(dotv[d][i], 1);

    float nrm[3][6];
#pragma unroll
    for (int r = 0; r < 3; ++r)
#pragma unroll
        for (int j = 0; j < 6; ++j) nrm[r][j] = __builtin_amdgcn_sqrtf(sq[r][j]);

    float w[8][4];
    float simarr[4];
#pragma unroll
    for (int i = 0; i < 4; ++i) {
        float s[8];
        const float cn = nrm[1][i + 1];
        float tot = 0.f, cnt = 0.f;
        int d = 0;
#pragma unroll
        for (int dyi = 0; dyi < 3; ++dyi)
#pragma unroll
            for (int dxi = 0; dxi < 3; ++dxi) {
                if (dyi == 1 && dxi == 1) continue;
                const bool m = rowok[dyi] && colok[i + dxi];
                const float den = fmaxf(cn * nrm[dyi][i + dxi], EPSV);
                const float cs = dotv[d][i] * __builtin_amdgcn_rcpf(den);
                s[d] = m ? cs : 0.f;
                tot += s[d];
                cnt += m ? 1.f : 0.f;
                ++d;
            }
        simarr[i] = tot * __builtin_amdgcn_rcpf(cnt);
        if (COMPUTE_NEXT) {
            float mx = s[0];
#pragma unroll
            for (int d2 = 1; d2 < 8; ++d2) mx = fmaxf(mx, s[d2]);
            float wsum = 0.f;
#pragma unroll
            for (int d2 = 0; d2 < 8; ++d2) { w[d2][i] = __expf(s[d2] - mx); wsum += w[d2][i]; }
            const float inv = __builtin_amdgcn_rcpf(wsum);
#pragma unroll
            for (int d2 = 0; d2 < 8; ++d2) w[d2][i] *= inv;
        }
    }
    if (half == 0) {
        float4 simv = { simarr[0], simarr[1], simarr[2], simarr[3] };
        *reinterpret_cast<float4*>(simout + b * HWSZ + y * WW + x0) = simv;
    }

    // ---------------- Pass 2: weighted neighbor average (own 16 channels) ----
    if (COMPUTE_NEXT) {
        float* outp = Fn + (size_t)b * IMGSZ + (size_t)c0 * HWSZ + y * WW + x0;
        float va[3][6], vb[3][6];
        load_halo_sh(base, ym, yp, xl, xr, tx, egbase, va);
        for (int c = 0; c < NCH; c += 2) {
            load_halo_sh(base + (c + 1) * HWSZ, ym, yp, xl, xr, tx,
                         egbase + (c + 1) * 8, vb);
            {
                float o[4] = { 0.f, 0.f, 0.f, 0.f };
                acc_pass2(va, w, o);
                float4 ov = { o[0], o[1], o[2], o[3] };
                *reinterpret_cast<float4*>(outp + c * HWSZ) = ov;
            }
            if (c + 2 < NCH) load_halo_sh(base + (c + 2) * HWSZ, ym, yp, xl, xr, tx,
                                          egbase + (c + 2) * 8, va);
            {
                float o[4] = { 0.f, 0.f, 0.f, 0.f };
                acc_pass2(vb, w, o);
                float4 ov = { o[0], o[1], o[2], o[3] };
                *reinterpret_cast<float4*>(outp + (c + 1) * HWSZ) = ov;
            }
        }
    }
}

// out[g][t][p] = 0.25 * sum_{i<4} sims[tt][4g+i][p], tt = {0,0,1,2}[t]
__global__ __launch_bounds__(256) void reduce_kernel(const float* __restrict__ sims,
                                                     float* __restrict__ out)
{
    const int idx = blockIdx.x * blockDim.x + threadIdx.x;  // 131072 float4s
    const int p4 = idx & (HWSZ / 4 - 1);
    const int t  = (idx >> 14) & 3;
    const int g  = idx >> 16;
    const int tt = (t <= 1) ? 0 : (t - 1);
    const float4* s = reinterpret_cast<const float4*>(sims) +
                      (size_t)(tt * NIMG + g * 4) * (HWSZ / 4) + p4;
    float4 a = s[0];
    float4 b = s[HWSZ / 4];
    float4 c = s[2 * (HWSZ / 4)];
    float4 d = s[3 * (HWSZ / 4)];
    float4 o;
    o.x = 0.25f * (a.x + b.x + c.x + d.x);
    o.y = 0.25f * (a.y + b.y + c.y + d.y);
    o.z = 0.25f * (a.z + b.z + c.z + d.z);
    o.w = 0.25f * (a.w + b.w + c.w + d.w);
    reinterpret_cast<float4*>(out)[idx] = o;
}

extern "C" void kernel_launch(void* const* d_in, const int* in_sizes, int n_in,
                              void* d_out, int out_size, void* d_ws, size_t ws_size,
                              hipStream_t stream)
{
    const float* F0 = (const float*)d_in[0];
    float* F1   = (float*)d_ws;                       // 64 MB
    float* F2   = F1 + (size_t)NIMG * IMGSZ;          // 64 MB
    float* sims = F2 + (size_t)NIMG * IMGSZ;          // 6 MB

    dim3 block(256);
    dim3 grid(HH / 2, NIMG);

    hipLaunchKernelGGL((step_kernel<true>),  grid, block, 0, stream, F0, F1, sims);
    hipLaunchKernelGGL((step_kernel<true>),  grid, block, 0, stream, F1, F2, sims + (size_t)NIMG * HWSZ);
    hipLaunchKernelGGL((step_kernel<false>), grid, block, 0, stream, F2, nullptr, sims + (size_t)2 * NIMG * HWSZ);

    hipLaunchKernelGGL(reduce_kernel, dim3((2 * 4 * HWSZ / 4) / 256), block, 0, stream,
                       sims, (float*)d_out);
}

// Round 11
// 152.333 us; speedup vs baseline: 4.8358x; 1.1519x over previous
//
#include <hip/hip_runtime.h>

#define HH 256
#define WW 256
#define CC 32
#define HWSZ (HH * WW)
#define IMGSZ (CC * HWSZ)
#define NIMG 8
#define EPSV 1e-8f
#define NCH (CC / 2)   // channels per lane (2-way channel split)

typedef float v2f __attribute__((ext_vector_type(2)));

__device__ __forceinline__ v2f fma2(v2f a, v2f b, v2f c) {
    return __builtin_elementwise_fma(a, b, c);
}

// Halo for one channel around this lane's 4 px (R3-proven, unchanged).
__device__ __forceinline__ void load_halo_sh(const float* __restrict__ p,
                                             bool ym, bool yp, bool xl, bool xr,
                                             int tx, float v[3][6])
{
    const bool rowok[3] = { ym, true, yp };
#pragma unroll
    for (int r = 0; r < 3; ++r) {
        const float* row = p + (r - 1) * WW;
        float4 m;
        if (rowok[r]) m = *reinterpret_cast<const float4*>(row);
        else { m.x = m.y = m.z = m.w = 0.f; }
        v[r][1] = m.x; v[r][2] = m.y; v[r][3] = m.z; v[r][4] = m.w;
        float lm = __shfl_up(m.w, 2);
        float rm = __shfl_down(m.x, 2);
        if (tx == 0)  lm = (xl && rowok[r]) ? row[-1] : 0.f;
        if (tx == 31) rm = (xr && rowok[r]) ? row[4]  : 0.f;
        v[r][0] = lm;
        v[r][5] = rm;
    }
}

// Packed pass-1: 18 squares as 9 pk-FMA, 32 dot-FMAs as 16 pk-FMA.
// Window pairs p_j = {v[r][j], v[r][j+1]}; pairs 1,2,3 are contiguous float4
// components (register-pair friendly for VOP3P).
__device__ __forceinline__ void acc_pass1(const float v[3][6],
                                          v2f sq2[3][3], v2f dv2[8][2])
{
    const v2f c0 = { v[1][1], v[1][2] };
    const v2f c1 = { v[1][3], v[1][4] };
#pragma unroll
    for (int r = 0; r < 3; ++r) {
        const v2f p0 = { v[r][0], v[r][1] };
        const v2f p1 = { v[r][1], v[r][2] };
        const v2f p2 = { v[r][2], v[r][3] };
        const v2f p3 = { v[r][3], v[r][4] };
        const v2f p4 = { v[r][4], v[r][5] };
        sq2[r][0] = fma2(p0, p0, sq2[r][0]);
        sq2[r][1] = fma2(p2, p2, sq2[r][1]);
        sq2[r][2] = fma2(p4, p4, sq2[r][2]);
        if (r == 1) {
            dv2[3][0] = fma2(c0, p0, dv2[3][0]);   // W
            dv2[3][1] = fma2(c1, p2, dv2[3][1]);
            dv2[4][0] = fma2(c0, p2, dv2[4][0]);   // E
            dv2[4][1] = fma2(c1, p4, dv2[4][1]);
        } else {
            const int db = (r == 0) ? 0 : 5;       // NW/N/NE or SW/S/SE
            dv2[db + 0][0] = fma2(c0, p0, dv2[db + 0][0]);
            dv2[db + 0][1] = fma2(c1, p2, dv2[db + 0][1]);
            dv2[db + 1][0] = fma2(c0, p1, dv2[db + 1][0]);
            dv2[db + 1][1] = fma2(c1, p3, dv2[db + 1][1]);
            dv2[db + 2][0] = fma2(c0, p2, dv2[db + 2][0]);
            dv2[db + 2][1] = fma2(c1, p4, dv2[db + 2][1]);
        }
    }
}

// Packed pass-2: 32 weighted FMAs as 16 pk-FMA.
__device__ __forceinline__ void acc_pass2(const float v[3][6],
                                          const v2f w2[8][2], v2f o2[2])
{
    int d = 0;
#pragma unroll
    for (int dyi = 0; dyi < 3; ++dyi)
#pragma unroll
        for (int dxi = 0; dxi < 3; ++dxi) {
            if (dyi == 1 && dxi == 1) continue;
            const v2f n0 = { v[dyi][dxi],     v[dyi][dxi + 1] };
            const v2f n1 = { v[dyi][dxi + 2], v[dyi][dxi + 3] };
            o2[0] = fma2(w2[d][0], n0, o2[0]);
            o2[1] = fma2(w2[d][1], n1, o2[1]);
            ++d;
        }
}

// Lane pairing (R3): lane&1 = channel half (16 ch), lane>>1 = px group (4 px).
// Wave = 128 px (half row); block = 4 waves = 2 rows.
template <bool COMPUTE_NEXT>
__global__ __launch_bounds__(256, 4) void step_kernel(const float* __restrict__ F,
                                                      float* __restrict__ Fn,
                                                      float* __restrict__ simout)
{
    // Bijective XCD remap: 1024 blocks, each XCD owns one image.
    const int linear = blockIdx.y * (HH / 2) + blockIdx.x;   // 0..1023
    const int remap  = (linear & 7) * 128 + (linear >> 3);
    const int b      = remap >> 7;
    const int rowblk = remap & 127;

    const int tid  = threadIdx.x;
    const int wave = tid >> 6;
    const int lane = tid & 63;
    const int half = lane & 1;
    const int tx   = lane >> 1;            // 0..31
    const int y    = rowblk * 2 + (wave >> 1);
    const int x0   = (wave & 1) * 128 + (tx << 2);
    const int c0   = half * NCH;

    const bool ym = y > 0, yp = y < HH - 1;
    const bool xl = x0 > 0, xr = x0 < WW - 4;
    const bool rowok[3] = { ym, true, yp };
    const bool colok[6] = { xl, true, true, true, true, xr };

    const float* base = F + (size_t)b * IMGSZ + (size_t)c0 * HWSZ + y * WW + x0;

    // ---------------- Pass 1: partial norms + dots over 16 channels ----------
    v2f sq2[3][3];
    v2f dv2[8][2];
#pragma unroll
    for (int r = 0; r < 3; ++r)
#pragma unroll
        for (int k = 0; k < 3; ++k) sq2[r][k] = (v2f){ 0.f, 0.f };
#pragma unroll
    for (int d = 0; d < 8; ++d)
#pragma unroll
        for (int k = 0; k < 2; ++k) dv2[d][k] = (v2f){ 0.f, 0.f };

    {
        float va[3][6], vb[3][6];
        load_halo_sh(base, ym, yp, xl, xr, tx, va);
        for (int c = 0; c < NCH; c += 2) {
            load_halo_sh(base + (c + 1) * HWSZ, ym, yp, xl, xr, tx, vb);
            acc_pass1(va, sq2, dv2);
            if (c + 2 < NCH) load_halo_sh(base + (c + 2) * HWSZ, ym, yp, xl, xr, tx, va);
            acc_pass1(vb, sq2, dv2);
        }
    }

    // Merge the two channel halves (paired lanes) -> scalar accumulators.
    float sqs[3][6];
    float dotv[8][4];
#pragma unroll
    for (int r = 0; r < 3; ++r)
#pragma unroll
        for (int k = 0; k < 3; ++k) {
            float a0 = sq2[r][k][0], a1 = sq2[r][k][1];
            sqs[r][2 * k + 0] = a0 + __shfl_xor(a0, 1);
            sqs[r][2 * k + 1] = a1 + __shfl_xor(a1, 1);
        }
#pragma unroll
    for (int d = 0; d < 8; ++d)
#pragma unroll
        for (int k = 0; k < 2; ++k) {
            float a0 = dv2[d][k][0], a1 = dv2[d][k][1];
            dotv[d][2 * k + 0] = a0 + __shfl_xor(a0, 1);
            dotv[d][2 * k + 1] = a1 + __shfl_xor(a1, 1);
        }

    float nrm[3][6];
#pragma unroll
    for (int r = 0; r < 3; ++r)
#pragma unroll
        for (int j = 0; j < 6; ++j) nrm[r][j] = __builtin_amdgcn_sqrtf(sqs[r][j]);

    float w[8][4];
    float simarr[4];
#pragma unroll
    for (int i = 0; i < 4; ++i) {
        float s[8];
        const float cn = nrm[1][i + 1];
        float tot = 0.f, cnt = 0.f;
        int d = 0;
#pragma unroll
        for (int dyi = 0; dyi < 3; ++dyi)
#pragma unroll
            for (int dxi = 0; dxi < 3; ++dxi) {
                if (dyi == 1 && dxi == 1) continue;
                const bool m = rowok[dyi] && colok[i + dxi];
                const float den = fmaxf(cn * nrm[dyi][i + dxi], EPSV);
                const float cs = dotv[d][i] * __builtin_amdgcn_rcpf(den);
                s[d] = m ? cs : 0.f;
                tot += s[d];
                cnt += m ? 1.f : 0.f;
                ++d;
            }
        simarr[i] = tot * __builtin_amdgcn_rcpf(cnt);
        if (COMPUTE_NEXT) {
            float mx = s[0];
#pragma unroll
            for (int d2 = 1; d2 < 8; ++d2) mx = fmaxf(mx, s[d2]);
            float wsum = 0.f;
#pragma unroll
            for (int d2 = 0; d2 < 8; ++d2) { w[d2][i] = __expf(s[d2] - mx); wsum += w[d2][i]; }
            const float inv = __builtin_amdgcn_rcpf(wsum);
#pragma unroll
            for (int d2 = 0; d2 < 8; ++d2) w[d2][i] *= inv;
        }
    }
    if (half == 0) {
        float4 simv = { simarr[0], simarr[1], simarr[2], simarr[3] };
        *reinterpret_cast<float4*>(simout + b * HWSZ + y * WW + x0) = simv;
    }

    // ---------------- Pass 2: weighted neighbor average (own 16 channels) ----
    if (COMPUTE_NEXT) {
        v2f w2[8][2];
#pragma unroll
        for (int d = 0; d < 8; ++d) {
            w2[d][0] = (v2f){ w[d][0], w[d][1] };
            w2[d][1] = (v2f){ w[d][2], w[d][3] };
        }
        float* outp = Fn + (size_t)b * IMGSZ + (size_t)c0 * HWSZ + y * WW + x0;
        float va[3][6], vb[3][6];
        load_halo_sh(base, ym, yp, xl, xr, tx, va);
        for (int c = 0; c < NCH; c += 2) {
            load_halo_sh(base + (c + 1) * HWSZ, ym, yp, xl, xr, tx, vb);
            {
                v2f o2[2] = { { 0.f, 0.f }, { 0.f, 0.f } };
                acc_pass2(va, w2, o2);
                float4 ov = { o2[0][0], o2[0][1], o2[1][0], o2[1][1] };
                *reinterpret_cast<float4*>(outp + c * HWSZ) = ov;
            }
            if (c + 2 < NCH) load_halo_sh(base + (c + 2) * HWSZ, ym, yp, xl, xr, tx, va);
            {
                v2f o2[2] = { { 0.f, 0.f }, { 0.f, 0.f } };
                acc_pass2(vb, w2, o2);
                float4 ov = { o2[0][0], o2[0][1], o2[1][0], o2[1][1] };
                *reinterpret_cast<float4*>(outp + (c + 1) * HWSZ) = ov;
            }
        }
    }
}

// out[g][t][p] = 0.25 * sum_{i<4} sims[tt][4g+i][p], tt = {0,0,1,2}[t]
__global__ __launch_bounds__(256) void reduce_kernel(const float* __restrict__ sims,
                                                     float* __restrict__ out)
{
    const int idx = blockIdx.x * blockDim.x + threadIdx.x;  // 131072 float4s
    const int p4 = idx & (HWSZ / 4 - 1);
    const int t  = (idx >> 14) & 3;
    const int g  = idx >> 16;
    const int tt = (t <= 1) ? 0 : (t - 1);
    const float4* s = reinterpret_cast<const float4*>(sims) +
                      (size_t)(tt * NIMG + g * 4) * (HWSZ / 4) + p4;
    float4 a = s[0];
    float4 b = s[HWSZ / 4];
    float4 c = s[2 * (HWSZ / 4)];
    float4 d = s[3 * (HWSZ / 4)];
    float4 o;
    o.x = 0.25f * (a.x + b.x + c.x + d.x);
    o.y = 0.25f * (a.y + b.y + c.y + d.y);
    o.z = 0.25f * (a.z + b.z + c.z + d.z);
    o.w = 0.25f * (a.w + b.w + c.w + d.w);
    reinterpret_cast<float4*>(out)[idx] = o;
}

extern "C" void kernel_launch(void* const* d_in, const int* in_sizes, int n_in,
                              void* d_out, int out_size, void* d_ws, size_t ws_size,
                              hipStream_t stream)
{
    const float* F0 = (const float*)d_in[0];
    float* F1   = (float*)d_ws;                       // 64 MB
    float* F2   = F1 + (size_t)NIMG * IMGSZ;          // 64 MB
    float* sims = F2 + (size_t)NIMG * IMGSZ;          // 6 MB

    dim3 block(256);
    dim3 grid(HH / 2, NIMG);

    hipLaunchKernelGGL((step_kernel<true>),  grid, block, 0, stream, F0, F1, sims);
    hipLaunchKernelGGL((step_kernel<true>),  grid, block, 0, stream, F1, F2, sims + (size_t)NIMG * HWSZ);
    hipLaunchKernelGGL((step_kernel<false>), grid, block, 0, stream, F2, nullptr, sims + (size_t)2 * NIMG * HWSZ);

    hipLaunchKernelGGL(reduce_kernel, dim3((2 * 4 * HWSZ / 4) / 256), block, 0, stream,
                       sims, (float*)d_out);
}

// Round 12
// 111.529 us; speedup vs baseline: 6.6050x; 1.3659x over previous
//
#include <hip/hip_runtime.h>

#define HH 256
#define WW 256
#define CC 32
#define HWSZ (HH * WW)
#define IMGSZ (CC * HWSZ)
#define NIMG 8
#define EPSV 1e-8f
#define NCH (CC / 2)   // channels per lane (2-way channel split)

__device__ __forceinline__ void acc_pass1(const float v[3][6],
                                          float sq[3][6], float dotv[8][4])
{
#pragma unroll
    for (int r = 0; r < 3; ++r)
#pragma unroll
        for (int j = 0; j < 6; ++j) sq[r][j] = fmaf(v[r][j], v[r][j], sq[r][j]);
    int d = 0;
#pragma unroll
    for (int dyi = 0; dyi < 3; ++dyi)
#pragma unroll
        for (int dxi = 0; dxi < 3; ++dxi) {
            if (dyi == 1 && dxi == 1) continue;
#pragma unroll
            for (int i = 0; i < 4; ++i)
                dotv[d][i] = fmaf(v[1][i + 1], v[dyi][i + dxi], dotv[d][i]);
            ++d;
        }
}

__device__ __forceinline__ void acc_pass2(const float v[3][6],
                                          const float w[8][4], float o[4])
{
    int d = 0;
#pragma unroll
    for (int dyi = 0; dyi < 3; ++dyi)
#pragma unroll
        for (int dxi = 0; dxi < 3; ++dxi) {
            if (dyi == 1 && dxi == 1) continue;
#pragma unroll
            for (int i = 0; i < 4; ++i)
                o[i] = fmaf(w[d][i], v[dyi][i + dxi], o[i]);
            ++d;
        }
}

// Async global -> LDS, 16 B per lane. LDS dest must be wave-uniform (HW adds
// lane*16); global source is per-lane.
__device__ __forceinline__ void gload16(const void* g, void* l)
{
    __builtin_amdgcn_global_load_lds(
        (const __attribute__((address_space(1))) void*)g,
        (__attribute__((address_space(3))) void*)l, 16, 0, 0);
}

// Stage slot SLOT: channel (SLOT&15) for half 0 and +16 for half 1 into slab
// buffer (SLOT&3). Each wave stages slab row `wave` (image row clamp(y0-1+wave)).
#define STAGE(SLOT) { \
    const int ch_ = (SLOT) & 15; \
    const int bo_ = ((SLOT) & 3) * 8192; \
    gload16(gsrc0 + (size_t)ch_ * HWSZ,        ldst0 + bo_); \
    gload16(gsrc0 + (size_t)(ch_ + 16) * HWSZ, ldst0 + bo_ + 4096); }

// Counted-vmcnt wait + raw barrier (NOT __syncthreads: that drains vmcnt(0)
// and kills the pipeline). vmcnt(4) keeps the 2 newer stage slots in flight.
#define WAITB(VM) { asm volatile("s_waitcnt vmcnt(" #VM ")" ::: "memory"); \
                    __builtin_amdgcn_s_barrier(); }

// Read this lane's 3x6 window for slab buffer (G&3) and apply edge masks.
#define LOADV(G, VV) { \
    const char* sp_ = slabb + ((G) & 3) * 8192; \
    _Pragma("unroll") \
    for (int r_ = 0; r_ < 3; ++r_) { \
        float4 m_ = *(const float4*)(sp_ + bM + r_ * 1024); \
        float  l_ = *(const float*)(sp_ + bL + r_ * 1024); \
        float  q_ = *(const float*)(sp_ + bR + r_ * 1024); \
        const bool ok_ = rowok[r_]; \
        VV[r_][0] = (ok_ && xl) ? l_ : 0.f; \
        VV[r_][1] = ok_ ? m_.x : 0.f; \
        VV[r_][2] = ok_ ? m_.y : 0.f; \
        VV[r_][3] = ok_ ? m_.z : 0.f; \
        VV[r_][4] = ok_ ? m_.w : 0.f; \
        VV[r_][5] = (ok_ && xr) ? q_ : 0.f; \
    } }

// Lane pairing (R3): lane&1 = channel half (16 ch), lane>>1 = px group (4 px).
// Wave = 128 px (half row); block = 4 waves = 2 rows. All window data is
// LDS-staged; no shuffles, no scalar edge loads.
template <bool COMPUTE_NEXT>
__global__ __launch_bounds__(256, 3) void step_kernel(const float* __restrict__ F,
                                                      float* __restrict__ Fn,
                                                      float* __restrict__ simout)
{
    // Bijective XCD remap: 1024 blocks, each XCD owns one image.
    const int linear = blockIdx.y * (HH / 2) + blockIdx.x;   // 0..1023
    const int remap  = (linear & 7) * 128 + (linear >> 3);
    const int b      = remap >> 7;
    const int rowblk = remap & 127;

    const int tid  = threadIdx.x;
    const int wave = tid >> 6;
    const int lane = tid & 63;
    const int half = lane & 1;
    const int tx   = lane >> 1;            // 0..31
    const int y0   = rowblk * 2;
    const int y    = y0 + (wave >> 1);
    const int x0   = (wave & 1) * 128 + (tx << 2);
    const int c0   = half * NCH;

    // 32 KB: [buf4][half2][row4][256 cols] floats.
    __shared__ float4 slab4[2048];
    char* slabb = (char*)slab4;

    const bool ym = y > 0, yp = y < HH - 1;
    const bool xl = x0 > 0, xr = x0 < WW - 4;
    const bool rowok[3] = { ym, true, yp };
    const bool colok[6] = { xl, true, true, true, true, xr };

    const float* Fb = F + (size_t)b * IMGSZ;

    // Staging invariants: this wave stages slab row `wave` = image row clamp(y0-1+wave).
    int arow = y0 - 1 + wave;
    arow = arow < 0 ? 0 : (arow > HH - 1 ? HH - 1 : arow);
    const float* gsrc0 = Fb + arow * WW + (lane << 2);
    char* ldst0 = slabb + wave * 1024;     // wave-uniform; +buf/half offsets in STAGE

    // ds-read invariants: rows (wave>>1)+{0,1,2}, cols x0-1 / x0..x0+3 / x0+4 (clamped).
    const int rbase = half * 4096 + (wave >> 1) * 1024;
    const int bM = rbase + x0 * 4;
    const int bL = rbase + (xl ? x0 * 4 - 4 : 0);
    const int bR = rbase + (xr ? x0 * 4 + 16 : 1020);

    // ---------------- Pass 1: partial norms + dots over 16 channels ----------
    float sq[3][6];
    float dotv[8][4];
#pragma unroll
    for (int r = 0; r < 3; ++r)
#pragma unroll
        for (int j = 0; j < 6; ++j) sq[r][j] = 0.f;
#pragma unroll
    for (int d = 0; d < 8; ++d)
#pragma unroll
        for (int i = 0; i < 4; ++i) dotv[d][i] = 0.f;

    STAGE(0) STAGE(1) STAGE(2)

#pragma unroll 1
    for (int g = 0; g < (COMPUTE_NEXT ? 16 : 13); ++g) {
        WAITB(4)
        STAGE(g + 3)                       // pass-1 tail slots 16..18 prefetch pass 2
        float v[3][6];
        LOADV(g, v)
        acc_pass1(v, sq, dotv);
    }
    if (!COMPUTE_NEXT) {                   // peeled tail, no further staging
        { WAITB(4) float v[3][6]; LOADV(13, v) acc_pass1(v, sq, dotv); }
        { WAITB(2) float v[3][6]; LOADV(14, v) acc_pass1(v, sq, dotv); }
        { WAITB(0) float v[3][6]; LOADV(15, v) acc_pass1(v, sq, dotv); }
    }

    // Merge the two channel halves (paired lanes).
#pragma unroll
    for (int r = 0; r < 3; ++r)
#pragma unroll
        for (int j = 0; j < 6; ++j) sq[r][j] += __shfl_xor(sq[r][j], 1);
#pragma unroll
    for (int d = 0; d < 8; ++d)
#pragma unroll
        for (int i = 0; i < 4; ++i) dotv[d][i] += __shfl_xor(dotv[d][i], 1);

    float nrm[3][6];
#pragma unroll
    for (int r = 0; r < 3; ++r)
#pragma unroll
        for (int j = 0; j < 6; ++j) nrm[r][j] = __builtin_amdgcn_sqrtf(sq[r][j]);

    float w[8][4];
    float simarr[4];
#pragma unroll
    for (int i = 0; i < 4; ++i) {
        float s[8];
        const float cn = nrm[1][i + 1];
        float tot = 0.f, cnt = 0.f;
        int d = 0;
#pragma unroll
        for (int dyi = 0; dyi < 3; ++dyi)
#pragma unroll
            for (int dxi = 0; dxi < 3; ++dxi) {
                if (dyi == 1 && dxi == 1) continue;
                const bool m = rowok[dyi] && colok[i + dxi];
                const float den = fmaxf(cn * nrm[dyi][i + dxi], EPSV);
                const float cs = dotv[d][i] * __builtin_amdgcn_rcpf(den);
                s[d] = m ? cs : 0.f;
                tot += s[d];
                cnt += m ? 1.f : 0.f;
                ++d;
            }
        simarr[i] = tot * __builtin_amdgcn_rcpf(cnt);
        if (COMPUTE_NEXT) {
            float mx = s[0];
#pragma unroll
            for (int d2 = 1; d2 < 8; ++d2) mx = fmaxf(mx, s[d2]);
            float wsum = 0.f;
#pragma unroll
            for (int d2 = 0; d2 < 8; ++d2) { w[d2][i] = __expf(s[d2] - mx); wsum += w[d2][i]; }
            const float inv = __builtin_amdgcn_rcpf(wsum);
#pragma unroll
            for (int d2 = 0; d2 < 8; ++d2) w[d2][i] *= inv;
        }
    }
    if (half == 0) {
        float4 simv = { simarr[0], simarr[1], simarr[2], simarr[3] };
        *reinterpret_cast<float4*>(simout + b * HWSZ + y * WW + x0) = simv;
    }

    // ---------------- Pass 2: weighted neighbor average (own 16 channels) ----
    if (COMPUTE_NEXT) {
        float* outp = Fn + (size_t)b * IMGSZ + (size_t)c0 * HWSZ + y * WW + x0;
#pragma unroll 1
        for (int g = 16; g < 29; ++g) {
            WAITB(4)
            STAGE(g + 3)
            float v[3][6];
            LOADV(g, v)
            float o[4] = { 0.f, 0.f, 0.f, 0.f };
            acc_pass2(v, w, o);
            float4 ov = { o[0], o[1], o[2], o[3] };
            *reinterpret_cast<float4*>(outp + (g & 15) * HWSZ) = ov;
        }
        { WAITB(4) float v[3][6]; LOADV(29, v)
          float o[4] = { 0.f, 0.f, 0.f, 0.f }; acc_pass2(v, w, o);
          float4 ov = { o[0], o[1], o[2], o[3] };
          *reinterpret_cast<float4*>(outp + 13 * HWSZ) = ov; }
        { WAITB(2) float v[3][6]; LOADV(30, v)
          float o[4] = { 0.f, 0.f, 0.f, 0.f }; acc_pass2(v, w, o);
          float4 ov = { o[0], o[1], o[2], o[3] };
          *reinterpret_cast<float4*>(outp + 14 * HWSZ) = ov; }
        { WAITB(0) float v[3][6]; LOADV(31, v)
          float o[4] = { 0.f, 0.f, 0.f, 0.f }; acc_pass2(v, w, o);
          float4 ov = { o[0], o[1], o[2], o[3] };
          *reinterpret_cast<float4*>(outp + 15 * HWSZ) = ov; }
    }
}

// out[g][t][p] = 0.25 * sum_{i<4} sims[tt][4g+i][p], tt = {0,0,1,2}[t]
__global__ __launch_bounds__(256) void reduce_kernel(const float* __restrict__ sims,
                                                     float* __restrict__ out)
{
    const int idx = blockIdx.x * blockDim.x + threadIdx.x;  // 131072 float4s
    const int p4 = idx & (HWSZ / 4 - 1);
    const int t  = (idx >> 14) & 3;
    const int g  = idx >> 16;
    const int tt = (t <= 1) ? 0 : (t - 1);
    const float4* s = reinterpret_cast<const float4*>(sims) +
                      (size_t)(tt * NIMG + g * 4) * (HWSZ / 4) + p4;
    float4 a = s[0];
    float4 b = s[HWSZ / 4];
    float4 c = s[2 * (HWSZ / 4)];
    float4 d = s[3 * (HWSZ / 4)];
    float4 o;
    o.x = 0.25f * (a.x + b.x + c.x + d.x);
    o.y = 0.25f * (a.y + b.y + c.y + d.y);
    o.z = 0.25f * (a.z + b.z + c.z + d.z);
    o.w = 0.25f * (a.w + b.w + c.w + d.w);
    reinterpret_cast<float4*>(out)[idx] = o;
}

extern "C" void kernel_launch(void* const* d_in, const int* in_sizes, int n_in,
                              void* d_out, int out_size, void* d_ws, size_t ws_size,
                              hipStream_t stream)
{
    const float* F0 = (const float*)d_in[0];
    float* F1   = (float*)d_ws;                       // 64 MB
    float* F2   = F1 + (size_t)NIMG * IMGSZ;          // 64 MB
    float* sims = F2 + (size_t)NIMG * IMGSZ;          // 6 MB

    dim3 block(256);
    dim3 grid(HH / 2, NIMG);

    hipLaunchKernelGGL((step_kernel<true>),  grid, block, 0, stream, F0, F1, sims);
    hipLaunchKernelGGL((step_kernel<true>),  grid, block, 0, stream, F1, F2, sims + (size_t)NIMG * HWSZ);
    hipLaunchKernelGGL((step_kernel<false>), grid, block, 0, stream, F2, nullptr, sims + (size_t)2 * NIMG * HWSZ);

    hipLaunchKernelGGL(reduce_kernel, dim3((2 * 4 * HWSZ / 4) / 256), block, 0, stream,
                       sims, (float*)d_out);
}

// Round 13
// 109.159 us; speedup vs baseline: 6.7484x; 1.0217x over previous
//
#include <hip/hip_runtime.h>

#define HH 256
#define WW 256
#define CC 32
#define HWSZ (HH * WW)
#define IMGSZ (CC * HWSZ)
#define NIMG 8
#define EPSV 1e-8f
#define NCH (CC / 2)   // channels per lane (2-way channel split)

__device__ __forceinline__ void acc_pass1(const float v[3][6],
                                          float sq[3][6], float dotv[8][4])
{
#pragma unroll
    for (int r = 0; r < 3; ++r)
#pragma unroll
        for (int j = 0; j < 6; ++j) sq[r][j] = fmaf(v[r][j], v[r][j], sq[r][j]);
    int d = 0;
#pragma unroll
    for (int dyi = 0; dyi < 3; ++dyi)
#pragma unroll
        for (int dxi = 0; dxi < 3; ++dxi) {
            if (dyi == 1 && dxi == 1) continue;
#pragma unroll
            for (int i = 0; i < 4; ++i)
                dotv[d][i] = fmaf(v[1][i + 1], v[dyi][i + dxi], dotv[d][i]);
            ++d;
        }
}

__device__ __forceinline__ void acc_pass2(const float v[3][6],
                                          const float w[8][4], float o[4])
{
    int d = 0;
#pragma unroll
    for (int dyi = 0; dyi < 3; ++dyi)
#pragma unroll
        for (int dxi = 0; dxi < 3; ++dxi) {
            if (dyi == 1 && dxi == 1) continue;
#pragma unroll
            for (int i = 0; i < 4; ++i)
                o[i] = fmaf(w[d][i], v[dyi][i + dxi], o[i]);
            ++d;
        }
}

// Async global -> LDS, 16 B per lane. LDS dest is wave-uniform (HW adds
// lane*16); global source is per-lane.
__device__ __forceinline__ void gload16(const void* g, void* l)
{
    __builtin_amdgcn_global_load_lds(
        (const __attribute__((address_space(1))) void*)g,
        (__attribute__((address_space(3))) void*)l, 16, 0, 0);
}

// Stage slot SLOT: channel (SLOT&15) for half 0 and +16 for half 1 into slab
// buffer (SLOT&3). Each wave stages slab row `wave` (image row clamp(y0-1+wave)).
#define STAGE(SLOT) { \
    const int ch_ = (SLOT) & 15; \
    const int bo_ = ((SLOT) & 3) * 8192; \
    gload16(gsrc0 + (size_t)ch_ * HWSZ,        ldst0 + bo_); \
    gload16(gsrc0 + (size_t)(ch_ + 16) * HWSZ, ldst0 + bo_ + 4096); }

// Counted-vmcnt wait + raw barrier (NOT __syncthreads: that drains vmcnt(0)
// and kills the pipeline). vmcnt(4) keeps the 2 newer stage slots in flight.
#define WAITB(VM) { asm volatile("s_waitcnt vmcnt(" #VM ")" ::: "memory"); \
                    __builtin_amdgcn_s_barrier(); }

// Read this lane's 3x6 window from slab buffer (G&3). b128 at clean 16B
// stride per 32-lane half (conflict-free); x-halo via distance-1 shuffles;
// LDS scalar only on the 4 edge lanes (predicated -> no bank pressure).
#define LOADV(G, VV) { \
    const char* sp_ = slabb + ((G) & 3) * 8192; \
    _Pragma("unroll") \
    for (int r_ = 0; r_ < 3; ++r_) { \
        float4 m_ = *(const float4*)(sp_ + bM + r_ * 1024); \
        float e_ = 0.f; \
        if (edge) e_ = *(const float*)(sp_ + bE + r_ * 1024); \
        const float lu_ = __shfl_up(m_.w, 1); \
        const float rd_ = __shfl_down(m_.x, 1); \
        const bool ok_ = rowok[r_]; \
        VV[r_][0] = (ok_ && xl) ? ((tx == 0)  ? e_ : lu_) : 0.f; \
        VV[r_][1] = ok_ ? m_.x : 0.f; \
        VV[r_][2] = ok_ ? m_.y : 0.f; \
        VV[r_][3] = ok_ ? m_.z : 0.f; \
        VV[r_][4] = ok_ ? m_.w : 0.f; \
        VV[r_][5] = (ok_ && xr) ? ((tx == 31) ? e_ : rd_) : 0.f; \
    } }

// Lane mapping: half = lane>>5 (16 channels each), tx = lane&31 (4 px each).
// Wave = 128 px (half row); block = 4 waves = 2 rows. All window data is
// LDS-staged via the counted-vmcnt async pipeline.
template <bool COMPUTE_NEXT>
__global__ __launch_bounds__(256, 4) void step_kernel(const float* __restrict__ F,
                                                      float* __restrict__ Fn,
                                                      float* __restrict__ simout)
{
    // Bijective XCD remap: 1024 blocks, each XCD owns one image.
    const int linear = blockIdx.y * (HH / 2) + blockIdx.x;   // 0..1023
    const int remap  = (linear & 7) * 128 + (linear >> 3);
    const int b      = remap >> 7;
    const int rowblk = remap & 127;

    const int tid  = threadIdx.x;
    const int wave = tid >> 6;
    const int lane = tid & 63;
    const int half = lane >> 5;            // channel half
    const int tx   = lane & 31;            // px group
    const int y0   = rowblk * 2;
    const int y    = y0 + (wave >> 1);
    const int x0   = (wave & 1) * 128 + (tx << 2);
    const int c0   = half * NCH;

    // 32 KB: [buf4][half2][row4][256 cols] floats.
    __shared__ float4 slab4[2048];
    char* slabb = (char*)slab4;

    const bool ym = y > 0, yp = y < HH - 1;
    const bool xl = x0 > 0, xr = x0 < WW - 4;
    const bool rowok[3] = { ym, true, yp };
    const bool colok[6] = { xl, true, true, true, true, xr };

    const float* Fb = F + (size_t)b * IMGSZ;

    // Staging invariants: this wave stages slab row `wave` = image row clamp(y0-1+wave).
    int arow = y0 - 1 + wave;
    arow = arow < 0 ? 0 : (arow > HH - 1 ? HH - 1 : arow);
    const float* gsrc0 = Fb + arow * WW + (lane << 2);
    char* ldst0 = slabb + wave * 1024;     // wave-uniform; +buf/half offsets in STAGE

    // ds-read invariants: rows (wave>>1)+{0,1,2} of own half.
    const int rbase = half * 4096 + (wave >> 1) * 1024;
    const int bM = rbase + x0 * 4;
    const int bL = rbase + (xl ? x0 * 4 - 4 : 0);
    const int bR = rbase + (xr ? x0 * 4 + 16 : 1020);
    const bool edge = (tx == 0) || (tx == 31);
    const int bE = (tx == 31) ? bR : bL;

    // ---------------- Pass 1: partial norms + dots over 16 channels ----------
    float sq[3][6];
    float dotv[8][4];
#pragma unroll
    for (int r = 0; r < 3; ++r)
#pragma unroll
        for (int j = 0; j < 6; ++j) sq[r][j] = 0.f;
#pragma unroll
    for (int d = 0; d < 8; ++d)
#pragma unroll
        for (int i = 0; i < 4; ++i) dotv[d][i] = 0.f;

    STAGE(0) STAGE(1) STAGE(2)

#pragma unroll 1
    for (int g = 0; g < (COMPUTE_NEXT ? 16 : 13); ++g) {
        WAITB(4)
        STAGE(g + 3)                       // pass-1 tail slots 16..18 prefetch pass 2
        float v[3][6];
        LOADV(g, v)
        acc_pass1(v, sq, dotv);
    }
    if (!COMPUTE_NEXT) {                   // peeled tail, no further staging
        { WAITB(4) float v[3][6]; LOADV(13, v) acc_pass1(v, sq, dotv); }
        { WAITB(2) float v[3][6]; LOADV(14, v) acc_pass1(v, sq, dotv); }
        { WAITB(0) float v[3][6]; LOADV(15, v) acc_pass1(v, sq, dotv); }
    }

    // Merge the two channel halves (lane bit 5).
#pragma unroll
    for (int r = 0; r < 3; ++r)
#pragma unroll
        for (int j = 0; j < 6; ++j) sq[r][j] += __shfl_xor(sq[r][j], 32);
#pragma unroll
    for (int d = 0; d < 8; ++d)
#pragma unroll
        for (int i = 0; i < 4; ++i) dotv[d][i] += __shfl_xor(dotv[d][i], 32);

    float nrm[3][6];
#pragma unroll
    for (int r = 0; r < 3; ++r)
#pragma unroll
        for (int j = 0; j < 6; ++j) nrm[r][j] = __builtin_amdgcn_sqrtf(sq[r][j]);

    float w[8][4];
    float simarr[4];
#pragma unroll
    for (int i = 0; i < 4; ++i) {
        float s[8];
        const float cn = nrm[1][i + 1];
        float tot = 0.f, cnt = 0.f;
        int d = 0;
#pragma unroll
        for (int dyi = 0; dyi < 3; ++dyi)
#pragma unroll
            for (int dxi = 0; dxi < 3; ++dxi) {
                if (dyi == 1 && dxi == 1) continue;
                const bool m = rowok[dyi] && colok[i + dxi];
                const float den = fmaxf(cn * nrm[dyi][i + dxi], EPSV);
                const float cs = dotv[d][i] * __builtin_amdgcn_rcpf(den);
                s[d] = m ? cs : 0.f;
                tot += s[d];
                cnt += m ? 1.f : 0.f;
                ++d;
            }
        simarr[i] = tot * __builtin_amdgcn_rcpf(cnt);
        if (COMPUTE_NEXT) {
            float mx = s[0];
#pragma unroll
            for (int d2 = 1; d2 < 8; ++d2) mx = fmaxf(mx, s[d2]);
            float wsum = 0.f;
#pragma unroll
            for (int d2 = 0; d2 < 8; ++d2) { w[d2][i] = __expf(s[d2] - mx); wsum += w[d2][i]; }
            const float inv = __builtin_amdgcn_rcpf(wsum);
#pragma unroll
            for (int d2 = 0; d2 < 8; ++d2) w[d2][i] *= inv;
        }
    }
    if (half == 0) {
        float4 simv = { simarr[0], simarr[1], simarr[2], simarr[3] };
        *reinterpret_cast<float4*>(simout + b * HWSZ + y * WW + x0) = simv;
    }

    // ---------------- Pass 2: weighted neighbor average (own 16 channels) ----
    if (COMPUTE_NEXT) {
        float* outp = Fn + (size_t)b * IMGSZ + (size_t)c0 * HWSZ + y * WW + x0;
#pragma unroll 1
        for (int g = 16; g < 29; ++g) {
            WAITB(4)
            STAGE(g + 3)
            float v[3][6];
            LOADV(g, v)
            float o[4] = { 0.f, 0.f, 0.f, 0.f };
            acc_pass2(v, w, o);
            float4 ov = { o[0], o[1], o[2], o[3] };
            *reinterpret_cast<float4*>(outp + (g & 15) * HWSZ) = ov;
        }
        { WAITB(4) float v[3][6]; LOADV(29, v)
          float o[4] = { 0.f, 0.f, 0.f, 0.f }; acc_pass2(v, w, o);
          float4 ov = { o[0], o[1], o[2], o[3] };
          *reinterpret_cast<float4*>(outp + 13 * HWSZ) = ov; }
        { WAITB(2) float v[3][6]; LOADV(30, v)
          float o[4] = { 0.f, 0.f, 0.f, 0.f }; acc_pass2(v, w, o);
          float4 ov = { o[0], o[1], o[2], o[3] };
          *reinterpret_cast<float4*>(outp + 14 * HWSZ) = ov; }
        { WAITB(0) float v[3][6]; LOADV(31, v)
          float o[4] = { 0.f, 0.f, 0.f, 0.f }; acc_pass2(v, w, o);
          float4 ov = { o[0], o[1], o[2], o[3] };
          *reinterpret_cast<float4*>(outp + 15 * HWSZ) = ov; }
    }
}

// out[g][t][p] = 0.25 * sum_{i<4} sims[tt][4g+i][p], tt = {0,0,1,2}[t]
__global__ __launch_bounds__(256) void reduce_kernel(const float* __restrict__ sims,
                                                     float* __restrict__ out)
{
    const int idx = blockIdx.x * blockDim.x + threadIdx.x;  // 131072 float4s
    const int p4 = idx & (HWSZ / 4 - 1);
    const int t  = (idx >> 14) & 3;
    const int g  = idx >> 16;
    const int tt = (t <= 1) ? 0 : (t - 1);
    const float4* s = reinterpret_cast<const float4*>(sims) +
                      (size_t)(tt * NIMG + g * 4) * (HWSZ / 4) + p4;
    float4 a = s[0];
    float4 b = s[HWSZ / 4];
    float4 c = s[2 * (HWSZ / 4)];
    float4 d = s[3 * (HWSZ / 4)];
    float4 o;
    o.x = 0.25f * (a.x + b.x + c.x + d.x);
    o.y = 0.25f * (a.y + b.y + c.y + d.y);
    o.z = 0.25f * (a.z + b.z + c.z + d.z);
    o.w = 0.25f * (a.w + b.w + c.w + d.w);
    reinterpret_cast<float4*>(out)[idx] = o;
}

extern "C" void kernel_launch(void* const* d_in, const int* in_sizes, int n_in,
                              void* d_out, int out_size, void* d_ws, size_t ws_size,
                              hipStream_t stream)
{
    const float* F0 = (const float*)d_in[0];
    float* F1   = (float*)d_ws;                       // 64 MB
    float* F2   = F1 + (size_t)NIMG * IMGSZ;          // 64 MB
    float* sims = F2 + (size_t)NIMG * IMGSZ;          // 6 MB

    dim3 block(256);
    dim3 grid(HH / 2, NIMG);

    hipLaunchKernelGGL((step_kernel<true>),  grid, block, 0, stream, F0, F1, sims);
    hipLaunchKernelGGL((step_kernel<true>),  grid, block, 0, stream, F1, F2, sims + (size_t)NIMG * HWSZ);
    hipLaunchKernelGGL((step_kernel<false>), grid, block, 0, stream, F2, nullptr, sims + (size_t)2 * NIMG * HWSZ);

    hipLaunchKernelGGL(reduce_kernel, dim3((2 * 4 * HWSZ / 4) / 256), block, 0, stream,
                       sims, (float*)d_out);
}

// Round 14
// 102.671 us; speedup vs baseline: 7.1749x; 1.0632x over previous
//
#include <hip/hip_runtime.h>

#define HH 256
#define WW 256
#define CC 32
#define HWSZ (HH * WW)
#define IMGSZ (CC * HWSZ)
#define NIMG 8
#define EPSV 1e-8f
#define NCH (CC / 2)   // channels per lane (2-way channel split)

__device__ __forceinline__ void acc_pass1(const float v[3][6],
                                          float sq[3][6], float dotv[8][4])
{
#pragma unroll
    for (int r = 0; r < 3; ++r)
#pragma unroll
        for (int j = 0; j < 6; ++j) sq[r][j] = fmaf(v[r][j], v[r][j], sq[r][j]);
    int d = 0;
#pragma unroll
    for (int dyi = 0; dyi < 3; ++dyi)
#pragma unroll
        for (int dxi = 0; dxi < 3; ++dxi) {
            if (dyi == 1 && dxi == 1) continue;
#pragma unroll
            for (int i = 0; i < 4; ++i)
                dotv[d][i] = fmaf(v[1][i + 1], v[dyi][i + dxi], dotv[d][i]);
            ++d;
        }
}

__device__ __forceinline__ void acc_pass2(const float v[3][6],
                                          const float w[8][4], float o[4])
{
    int d = 0;
#pragma unroll
    for (int dyi = 0; dyi < 3; ++dyi)
#pragma unroll
        for (int dxi = 0; dxi < 3; ++dxi) {
            if (dyi == 1 && dxi == 1) continue;
#pragma unroll
            for (int i = 0; i < 4; ++i)
                o[i] = fmaf(w[d][i], v[dyi][i + dxi], o[i]);
            ++d;
        }
}

// Async global -> LDS, 16 B per lane. LDS dest is wave-uniform (HW adds
// lane*16); global source is per-lane.
__device__ __forceinline__ void gload16(const void* g, void* l)
{
    __builtin_amdgcn_global_load_lds(
        (const __attribute__((address_space(1))) void*)g,
        (__attribute__((address_space(3))) void*)l, 16, 0, 0);
}

// Stage slot SLOT: channel (SLOT&15) for half 0 and +16 for half 1 into slab
// buffer (SLOT&3). Each wave stages slab row `wave` (image row clamp(y0-1+wave)).
#define STAGE(SLOT) { \
    const int ch_ = (SLOT) & 15; \
    const int bo_ = ((SLOT) & 3) * 8192; \
    gload16(gsrc0 + (size_t)ch_ * HWSZ,        ldst0 + bo_); \
    gload16(gsrc0 + (size_t)(ch_ + 16) * HWSZ, ldst0 + bo_ + 4096); }

// Counted-vmcnt wait + raw barrier (NOT __syncthreads: that drains vmcnt(0)
// and kills the pipeline). vmcnt(4) keeps the 2 newer stage slots in flight.
#define WAITB(VM) { asm volatile("s_waitcnt vmcnt(" #VM ")" ::: "memory"); \
                    __builtin_amdgcn_s_barrier(); }

// Read this lane's 3x6 window from slab buffer (G&3). b128 at clean 16B
// stride per 32-lane half (conflict-free); x-halo via distance-1 shuffles;
// LDS scalar only on the 4 edge lanes (predicated). Row masks fold away in
// the interior (YEDGE=false) instantiation.
#define LOADV(G, VV) { \
    const char* sp_ = slabb + ((G) & 3) * 8192; \
    _Pragma("unroll") \
    for (int r_ = 0; r_ < 3; ++r_) { \
        float4 m_ = *(const float4*)(sp_ + bM + r_ * 1024); \
        float e_ = 0.f; \
        if (edge) e_ = *(const float*)(sp_ + bE + r_ * 1024); \
        const float lu_ = __shfl_up(m_.w, 1); \
        const float rd_ = __shfl_down(m_.x, 1); \
        const bool ok_ = rowok[r_]; \
        VV[r_][0] = (ok_ && xl) ? ((tx == 0)  ? e_ : lu_) : 0.f; \
        VV[r_][1] = ok_ ? m_.x : 0.f; \
        VV[r_][2] = ok_ ? m_.y : 0.f; \
        VV[r_][3] = ok_ ? m_.z : 0.f; \
        VV[r_][4] = ok_ ? m_.w : 0.f; \
        VV[r_][5] = (ok_ && xr) ? ((tx == 31) ? e_ : rd_) : 0.f; \
    } }

// Lane mapping: half = lane>>5 (16 channels each), tx = lane&31 (4 px each).
// Wave = 128 px (half row); block = 4 waves = 2 rows. All window data is
// LDS-staged via the counted-vmcnt async pipeline. YEDGE=false (interior,
// 98.4% of blocks) folds all row-mask selects away.
template <bool YEDGE, bool COMPUTE_NEXT>
__device__ __forceinline__ void step_body(const float* __restrict__ F,
                                          float* __restrict__ Fn,
                                          float* __restrict__ simout,
                                          char* slabb, int b, int rowblk, int tid)
{
    const int wave = tid >> 6;
    const int lane = tid & 63;
    const int half = lane >> 5;            // channel half
    const int tx   = lane & 31;            // px group
    const int y0   = rowblk * 2;
    const int y    = y0 + (wave >> 1);
    const int x0   = (wave & 1) * 128 + (tx << 2);
    const int c0   = half * NCH;

    const bool ym = YEDGE ? (y > 0) : true;
    const bool yp = YEDGE ? (y < HH - 1) : true;
    const bool xl = x0 > 0, xr = x0 < WW - 4;
    const bool rowok[3] = { ym, true, yp };
    const bool colok[6] = { xl, true, true, true, true, xr };

    const float* Fb = F + (size_t)b * IMGSZ;

    // Staging invariants: this wave stages slab row `wave` = image row clamp(y0-1+wave).
    int arow = y0 - 1 + wave;
    if (YEDGE) arow = arow < 0 ? 0 : (arow > HH - 1 ? HH - 1 : arow);
    const float* gsrc0 = Fb + arow * WW + (lane << 2);
    char* ldst0 = slabb + wave * 1024;     // wave-uniform; +buf/half offsets in STAGE

    // ds-read invariants: rows (wave>>1)+{0,1,2} of own half.
    const int rbase = half * 4096 + (wave >> 1) * 1024;
    const int bM = rbase + x0 * 4;
    const int bL = rbase + (xl ? x0 * 4 - 4 : 0);
    const int bR = rbase + (xr ? x0 * 4 + 16 : 1020);
    const bool edge = (tx == 0) || (tx == 31);
    const int bE = (tx == 31) ? bR : bL;

    // ---------------- Pass 1: partial norms + dots over 16 channels ----------
    float sq[3][6];
    float dotv[8][4];
#pragma unroll
    for (int r = 0; r < 3; ++r)
#pragma unroll
        for (int j = 0; j < 6; ++j) sq[r][j] = 0.f;
#pragma unroll
    for (int d = 0; d < 8; ++d)
#pragma unroll
        for (int i = 0; i < 4; ++i) dotv[d][i] = 0.f;

    STAGE(0) STAGE(1) STAGE(2)

#pragma unroll 1
    for (int g = 0; g < (COMPUTE_NEXT ? 16 : 13); ++g) {
        WAITB(4)
        STAGE(g + 3)                       // pass-1 tail slots 16..18 prefetch pass 2
        float v[3][6];
        LOADV(g, v)
        acc_pass1(v, sq, dotv);
    }
    if (!COMPUTE_NEXT) {                   // peeled tail, no further staging
        { WAITB(4) float v[3][6]; LOADV(13, v) acc_pass1(v, sq, dotv); }
        { WAITB(2) float v[3][6]; LOADV(14, v) acc_pass1(v, sq, dotv); }
        { WAITB(0) float v[3][6]; LOADV(15, v) acc_pass1(v, sq, dotv); }
    }

    // Merge the two channel halves (lane bit 5).
#pragma unroll
    for (int r = 0; r < 3; ++r)
#pragma unroll
        for (int j = 0; j < 6; ++j) sq[r][j] += __shfl_xor(sq[r][j], 32);
#pragma unroll
    for (int d = 0; d < 8; ++d)
#pragma unroll
        for (int i = 0; i < 4; ++i) dotv[d][i] += __shfl_xor(dotv[d][i], 32);

    float nrm[3][6];
#pragma unroll
    for (int r = 0; r < 3; ++r)
#pragma unroll
        for (int j = 0; j < 6; ++j) nrm[r][j] = __builtin_amdgcn_sqrtf(sq[r][j]);

    float w[8][4];
    float simarr[4];
#pragma unroll
    for (int i = 0; i < 4; ++i) {
        float s[8];
        const float cn = nrm[1][i + 1];
        float tot = 0.f, cnt = 0.f;
        int d = 0;
#pragma unroll
        for (int dyi = 0; dyi < 3; ++dyi)
#pragma unroll
            for (int dxi = 0; dxi < 3; ++dxi) {
                if (dyi == 1 && dxi == 1) continue;
                const bool m = rowok[dyi] && colok[i + dxi];
                const float den = fmaxf(cn * nrm[dyi][i + dxi], EPSV);
                const float cs = dotv[d][i] * __builtin_amdgcn_rcpf(den);
                s[d] = m ? cs : 0.f;
                tot += s[d];
                cnt += m ? 1.f : 0.f;
                ++d;
            }
        simarr[i] = tot * __builtin_amdgcn_rcpf(cnt);
        if (COMPUTE_NEXT) {
            float mx = s[0];
#pragma unroll
            for (int d2 = 1; d2 < 8; ++d2) mx = fmaxf(mx, s[d2]);
            float wsum = 0.f;
#pragma unroll
            for (int d2 = 0; d2 < 8; ++d2) { w[d2][i] = __expf(s[d2] - mx); wsum += w[d2][i]; }
            const float inv = __builtin_amdgcn_rcpf(wsum);
#pragma unroll
            for (int d2 = 0; d2 < 8; ++d2) w[d2][i] *= inv;
        }
    }
    if (half == 0) {
        float4 simv = { simarr[0], simarr[1], simarr[2], simarr[3] };
        *reinterpret_cast<float4*>(simout + b * HWSZ + y * WW + x0) = simv;
    }

    // ---------------- Pass 2: weighted neighbor average (own 16 channels) ----
    if (COMPUTE_NEXT) {
        float* outp = Fn + (size_t)b * IMGSZ + (size_t)c0 * HWSZ + y * WW + x0;
#pragma unroll 1
        for (int g = 16; g < 29; ++g) {
            WAITB(4)
            STAGE(g + 3)
            float v[3][6];
            LOADV(g, v)
            float o[4] = { 0.f, 0.f, 0.f, 0.f };
            acc_pass2(v, w, o);
            float4 ov = { o[0], o[1], o[2], o[3] };
            *reinterpret_cast<float4*>(outp + (g & 15) * HWSZ) = ov;
        }
        { WAITB(4) float v[3][6]; LOADV(29, v)
          float o[4] = { 0.f, 0.f, 0.f, 0.f }; acc_pass2(v, w, o);
          float4 ov = { o[0], o[1], o[2], o[3] };
          *reinterpret_cast<float4*>(outp + 13 * HWSZ) = ov; }
        { WAITB(2) float v[3][6]; LOADV(30, v)
          float o[4] = { 0.f, 0.f, 0.f, 0.f }; acc_pass2(v, w, o);
          float4 ov = { o[0], o[1], o[2], o[3] };
          *reinterpret_cast<float4*>(outp + 14 * HWSZ) = ov; }
        { WAITB(0) float v[3][6]; LOADV(31, v)
          float o[4] = { 0.f, 0.f, 0.f, 0.f }; acc_pass2(v, w, o);
          float4 ov = { o[0], o[1], o[2], o[3] };
          *reinterpret_cast<float4*>(outp + 15 * HWSZ) = ov; }
    }
}

template <bool COMPUTE_NEXT>
__global__ __launch_bounds__(256, 4) void step_kernel(const float* __restrict__ F,
                                                      float* __restrict__ Fn,
                                                      float* __restrict__ simout)
{
    // Bijective XCD remap: 1024 blocks, each XCD owns one image.
    const int linear = blockIdx.y * (HH / 2) + blockIdx.x;   // 0..1023
    const int remap  = (linear & 7) * 128 + (linear >> 3);
    const int b      = remap >> 7;
    const int rowblk = remap & 127;

    // 32 KB: [buf4][half2][row4][256 cols] floats.
    __shared__ float4 slab4[2048];

    if (rowblk != 0 && rowblk != 127)      // block-uniform branch, no divergence
        step_body<false, COMPUTE_NEXT>(F, Fn, simout, (char*)slab4, b, rowblk, threadIdx.x);
    else
        step_body<true,  COMPUTE_NEXT>(F, Fn, simout, (char*)slab4, b, rowblk, threadIdx.x);
}

// out[g][t][p] = 0.25 * sum_{i<4} sims[tt][4g+i][p], tt = {0,0,1,2}[t]
__global__ __launch_bounds__(256) void reduce_kernel(const float* __restrict__ sims,
                                                     float* __restrict__ out)
{
    const int idx = blockIdx.x * blockDim.x + threadIdx.x;  // 131072 float4s
    const int p4 = idx & (HWSZ / 4 - 1);
    const int t  = (idx >> 14) & 3;
    const int g  = idx >> 16;
    const int tt = (t <= 1) ? 0 : (t - 1);
    const float4* s = reinterpret_cast<const float4*>(sims) +
                      (size_t)(tt * NIMG + g * 4) * (HWSZ / 4) + p4;
    float4 a = s[0];
    float4 b = s[HWSZ / 4];
    float4 c = s[2 * (HWSZ / 4)];
    float4 d = s[3 * (HWSZ / 4)];
    float4 o;
    o.x = 0.25f * (a.x + b.x + c.x + d.x);
    o.y = 0.25f * (a.y + b.y + c.y + d.y);
    o.z = 0.25f * (a.z + b.z + c.z + d.z);
    o.w = 0.25f * (a.w + b.w + c.w + d.w);
    reinterpret_cast<float4*>(out)[idx] = o;
}

extern "C" void kernel_launch(void* const* d_in, const int* in_sizes, int n_in,
                              void* d_out, int out_size, void* d_ws, size_t ws_size,
                              hipStream_t stream)
{
    const float* F0 = (const float*)d_in[0];
    float* F1   = (float*)d_ws;                       // 64 MB
    float* F2   = F1 + (size_t)NIMG * IMGSZ;          // 64 MB
    float* sims = F2 + (size_t)NIMG * IMGSZ;          // 6 MB

    dim3 block(256);
    dim3 grid(HH / 2, NIMG);

    hipLaunchKernelGGL((step_kernel<true>),  grid, block, 0, stream, F0, F1, sims);
    hipLaunchKernelGGL((step_kernel<true>),  grid, block, 0, stream, F1, F2, sims + (size_t)NIMG * HWSZ);
    hipLaunchKernelGGL((step_kernel<false>), grid, block, 0, stream, F2, nullptr, sims + (size_t)2 * NIMG * HWSZ);

    hipLaunchKernelGGL(reduce_kernel, dim3((2 * 4 * HWSZ / 4) / 256), block, 0, stream,
                       sims, (float*)d_out);
}